// Round 7
// baseline (118.105 us; speedup 1.0000x reference)
//
#include <hip/hip_runtime.h>
#include <stdint.h>

typedef unsigned short u16;
typedef unsigned int   u32;
typedef __attribute__((ext_vector_type(8)))  short bhalf8;   // 8 bf16 = 4 VGPRs
typedef __attribute__((ext_vector_type(16))) float f32x16;

#define B_ROWS 4096
#define I_DIM  1024
#define O_DIM  1024
#define N_D    6
#define K_LEG  (I_DIM * N_D)   /* 6144 */

#define BM 256
#define BN 256
#define BK 32
#define NU 56                   /* K-tiles per split (224 total / 4 splits) */
#define SLOT_BYTES 32768        /* A 16KB + B 16KB */
#define LDS_BYTES  131072       /* 4-slot ring */

// float -> bf16 round-to-nearest-even
__device__ __forceinline__ u16 f2b(float f) {
  u32 u = __float_as_uint(f);
  return (u16)((u + 0x7fffu + ((u >> 16) & 1u)) >> 16);
}

// async global->LDS, 16B per lane; LDS dest = wave-uniform base + lane*16
__device__ __forceinline__ void gld_lds16(const void* g, void* l) {
  __builtin_amdgcn_global_load_lds(
      (const __attribute__((address_space(1))) u32*)(uintptr_t)g,
      (__attribute__((address_space(3))) u32*)(u32)(uintptr_t)l, 16, 0, 0);
}

// ---- prep (merged): blocks [0,1024): Bb[o][i] = bf16(bw[i][o]) via 32x32 LDS tile
//                     blocks [1024,2048): Bl[o][i*6+d] = bf16(lw[i][o][d]) ----
#define RS 201
__global__ void k_prep_w(const float* __restrict__ bw, const float* __restrict__ lw,
                         u16* __restrict__ Bb, u16* __restrict__ Bl) {
  __shared__ float t[32 * RS];
  if (blockIdx.x < 1024) {
    const int bx = blockIdx.x & 31, by = blockIdx.x >> 5;
    const int i0 = by * 32, o0 = bx * 32;
    const int c = threadIdx.x & 31, r0 = threadIdx.x >> 5;
    #pragma unroll
    for (int k = 0; k < 4; ++k) {
      int r = r0 + k * 8;
      t[r * 33 + c] = bw[(size_t)(i0 + r) * O_DIM + o0 + c];
    }
    __syncthreads();
    #pragma unroll
    for (int k = 0; k < 4; ++k) {
      int r = r0 + k * 8;
      Bb[(size_t)(o0 + r) * I_DIM + i0 + c] = f2b(t[c * 33 + r]);
    }
  } else {
    const int blk = blockIdx.x - 1024;
    const int bx = blk & 31, by = blk >> 5;
    const int i0 = by * 32, o0 = bx * 32;
    for (int q = threadIdx.x; q < 32 * 48; q += 256) {
      int ri = q / 48, s4 = q % 48;
      float4 v = *(const float4*)(lw + (size_t)(i0 + ri) * (O_DIM * N_D) + o0 * N_D + s4 * 4);
      float* p = t + ri * RS + s4 * 4;
      p[0] = v.x; p[1] = v.y; p[2] = v.z; p[3] = v.w;
    }
    __syncthreads();
    for (int q = threadIdx.x; q < 32 * 96; q += 256) {
      int ro = q / 96, k = q % 96;
      int e0 = 2 * k, e1 = 2 * k + 1;
      float v0 = t[(e0 / 6) * RS + ro * 6 + (e0 % 6)];
      float v1 = t[(e1 / 6) * RS + ro * 6 + (e1 % 6)];
      u32* dst = (u32*)(Bl + (size_t)(o0 + ro) * K_LEG + i0 * N_D);
      dst[k] = (u32)f2b(v0) | ((u32)f2b(v1) << 16);
    }
  }
}

// ---- prep: per-row min/max, Legendre basis, x*P_d -> bf16 ----
__global__ void k_prep_basis(const float* __restrict__ x,
                             u16* __restrict__ Ab, u16* __restrict__ Al) {
  int b = blockIdx.x;
  int t = threadIdx.x;    // 256 threads, 4 elems each
  float4 v = ((const float4*)(x + (size_t)b * I_DIM))[t];
  float mn = fminf(fminf(v.x, v.y), fminf(v.z, v.w));
  float mx = fmaxf(fmaxf(v.x, v.y), fmaxf(v.z, v.w));
  #pragma unroll
  for (int off = 32; off > 0; off >>= 1) {
    mn = fminf(mn, __shfl_xor(mn, off, 64));
    mx = fmaxf(mx, __shfl_xor(mx, off, 64));
  }
  __shared__ float smn[4], smx[4];
  if ((t & 63) == 0) { smn[t >> 6] = mn; smx[t >> 6] = mx; }
  __syncthreads();
  mn = fminf(fminf(smn[0], smn[1]), fminf(smn[2], smn[3]));
  mx = fmaxf(fmaxf(smx[0], smx[1]), fmaxf(smx[2], smx[3]));
  float sc = 2.0f / (mx - mn + 1e-7f);

  float xs[4] = {v.x, v.y, v.z, v.w};
  u32 lb[12];
  #pragma unroll
  for (int e = 0; e < 4; ++e) {
    float xv = xs[e];
    float xn = (xv - mn) * sc - 1.0f;
    float p0 = 1.0f, p1 = xn;
    float p2 = (3.0f * xn * p1 - 1.0f * p0) * (1.0f / 2.0f);
    float p3 = (5.0f * xn * p2 - 2.0f * p1) * (1.0f / 3.0f);
    float p4 = (7.0f * xn * p3 - 3.0f * p2) * (1.0f / 4.0f);
    float p5 = (9.0f * xn * p4 - 4.0f * p3) * (1.0f / 5.0f);
    lb[e * 3 + 0] = (u32)f2b(xv * p0) | ((u32)f2b(xv * p1) << 16);
    lb[e * 3 + 1] = (u32)f2b(xv * p2) | ((u32)f2b(xv * p3) << 16);
    lb[e * 3 + 2] = (u32)f2b(xv * p4) | ((u32)f2b(xv * p5) << 16);
  }
  u32 a0 = (u32)f2b(xs[0]) | ((u32)f2b(xs[1]) << 16);
  u32 a1 = (u32)f2b(xs[2]) | ((u32)f2b(xs[3]) << 16);
  *(uint2*)(Ab + (size_t)b * I_DIM + t * 4) = make_uint2(a0, a1);
  uint4* dl = (uint4*)(Al + (size_t)b * K_LEG + t * 24);
  dl[0] = make_uint4(lb[0], lb[1], lb[2], lb[3]);
  dl[1] = make_uint4(lb[4], lb[5], lb[6], lb[7]);
  dl[2] = make_uint4(lb[8], lb[9], lb[10], lb[11]);
}

// ---- fused split-K=4 GEMM: 256x256 tile, 8 waves, 32x32x16 MFMA, 4-slot ring ----
// split 0: base(32 K-tiles) -> silu(acc) -> leg [0,24) -> plain store to out
// splits 1..3: leg [24+56(s-1), 24+56s)   -> plain store to P[s-1]
__global__ __launch_bounds__(512, 2) void k_gemm(
    const u16* __restrict__ Ab, const u16* __restrict__ Bb,
    const u16* __restrict__ Al, const u16* __restrict__ Bl,
    float* __restrict__ out, float* __restrict__ P) {
  extern __shared__ char lds[];

  const int tid  = threadIdx.x;
  const int wave = tid >> 6;
  const int lane = tid & 63;
  const int wm = wave >> 2;            // 0..1: 128-row band
  const int wn = wave & 3;             // 0..3: 64-col band
  const u32 lr = lane & 31;            // 32x32 frag row/col
  const u32 hi = (u32)lane >> 5;       // k half: k = hi*8 + j

  const int bid   = blockIdx.x;        // 256 blocks = 1/CU (128KB LDS forces 1/CU)
  const int bx    = bid >> 4;          // 0..15
  const int by    = (bid >> 2) & 3;    // 0..3
  const int split = bid & 3;
  const size_t brow = (size_t)bx * BM;
  const size_t bcol = (size_t)by * BN;
  const bool s0 = (split == 0);
  const int legbase = s0 ? 0 : (24 + 56 * (split - 1));

  // staging: thread t covers (row = r4, chunk = t&3) of each 128-row half;
  // source chunk pre-swizzled by (row>>1)&3 (verified 0-conflict key).
  const int r4 = tid >> 2;
  const size_t cs = (size_t)((((tid & 3) ^ ((r4 >> 1) & 3))) * 8);
  char* const l0 = lds + (u32)wave * 1024;

  // incremental staging pointers (rebuilt once at the base->leg boundary)
  const u16 *gA0, *gA1, *gB0, *gB1;
  auto set_ptrs = [&](const u16* A, const u16* Bt, size_t ldk, size_t kt) {
    const size_t ko = kt * BK + cs;
    gA0 = A  + (brow + r4) * ldk + ko;
    gA1 = A  + (brow + 128 + r4) * ldk + ko;
    gB0 = Bt + (bcol + r4) * ldk + ko;
    gB1 = Bt + (bcol + 128 + r4) * ldk + ko;
  };
  if (s0) set_ptrs(Ab, Bb, I_DIM, 0);
  else    set_ptrs(Al, Bl, K_LEG, (size_t)legbase);

  // frag-read byte offsets. Row r stored with chunk c at position c ^ ((r>>1)&3).
  // A-frag (m,kk): row = wm*128 + m*32 + lr  -> half wm, row-in-half m*32+lr
  // B-frag (n,kk): col = wn*64  + n*32 + lr  -> half wn>>1, row-in-half (wn&1)*64+n*32+lr
  // wanted chunk = kk*2 + hi; stored at (kk*2+hi) ^ ((lr>>1)&3)
  const u32 sxor   = (lr >> 1) & 3;
  const u32 chunk0 = ((0 + hi) ^ sxor) * 16;
  const u32 chunk1 = ((2 + hi) ^ sxor) * 16;
  const u32 abase_r = (u32)wm * 8192 + lr * 64;
  const u32 bbase_r = 16384u + ((u32)wn >> 1) * 8192 + ((u32)wn & 1) * 4096 + lr * 64;

  f32x16 acc[4][2] = {};
  bhalf8 af_[4], bf_[2];

  // prologue: fully stage tiles 0,1,2 (12 loads), advancing pointers each tile
  #pragma unroll
  for (int v = 0; v < 3; ++v) {
    char* d = l0 + (size_t)v * SLOT_BYTES;
    gld_lds16(gA0, d);          gld_lds16(gA1, d + 8192);
    gld_lds16(gB0, d + 16384);  gld_lds16(gB1, d + 24576);
    gA0 += BK; gA1 += BK; gB0 += BK; gB1 += BK;
  }
  asm volatile("s_waitcnt vmcnt(8)" ::: "memory");   // tile 0 landed
  __builtin_amdgcn_s_barrier();

  // Phase 0: read kk=0 frags (4 A + 2 B); stage A-halves of u+3; 8 MFMA (kk=0)
#define PH0(u, DO_STAGE) do {                                                 \
    const char* p_ = lds + (size_t)((u) & 3) * SLOT_BYTES;                    \
    _Pragma("unroll")                                                         \
    for (int n = 0; n < 2; ++n) bf_[n] = *(const bhalf8*)(p_ + bbase_r + n * 2048 + chunk0); \
    _Pragma("unroll")                                                         \
    for (int m = 0; m < 4; ++m) af_[m] = *(const bhalf8*)(p_ + abase_r + m * 2048 + chunk0); \
    if (DO_STAGE) {                                                           \
      char* d_ = l0 + (size_t)(((u) + 3) & 3) * SLOT_BYTES;                   \
      gld_lds16(gA0, d_); gld_lds16(gA1, d_ + 8192);                          \
    }                                                                         \
    asm volatile("" ::: "memory");                                            \
    __builtin_amdgcn_s_barrier();                                             \
    asm volatile("s_waitcnt lgkmcnt(0)" ::: "memory");                        \
    __builtin_amdgcn_sched_barrier(0);                                        \
    __builtin_amdgcn_s_setprio(1);                                            \
    _Pragma("unroll")                                                         \
    for (int m = 0; m < 4; ++m)                                               \
      _Pragma("unroll")                                                       \
      for (int n = 0; n < 2; ++n)                                             \
        acc[m][n] = __builtin_amdgcn_mfma_f32_32x32x16_bf16(af_[m], bf_[n], acc[m][n], 0, 0, 0); \
    __builtin_amdgcn_s_setprio(0);                                            \
    __builtin_amdgcn_s_barrier();                                             \
  } while (0)

  // Phase 1: read kk=1 frags; stage B-halves of u+3 + advance; vmcnt(VM); 8 MFMA (kk=1)
#define PH1(u, DO_STAGE, VM) do {                                             \
    const char* p_ = lds + (size_t)((u) & 3) * SLOT_BYTES;                    \
    _Pragma("unroll")                                                         \
    for (int n = 0; n < 2; ++n) bf_[n] = *(const bhalf8*)(p_ + bbase_r + n * 2048 + chunk1); \
    _Pragma("unroll")                                                         \
    for (int m = 0; m < 4; ++m) af_[m] = *(const bhalf8*)(p_ + abase_r + m * 2048 + chunk1); \
    if (DO_STAGE) {                                                           \
      char* d_ = l0 + (size_t)(((u) + 3) & 3) * SLOT_BYTES;                   \
      gld_lds16(gB0, d_ + 16384); gld_lds16(gB1, d_ + 24576);                 \
      if (s0 && (u) + 4 == 32) set_ptrs(Al, Bl, K_LEG, 0);                    \
      else { gA0 += BK; gA1 += BK; gB0 += BK; gB1 += BK; }                    \
    }                                                                         \
    asm volatile("s_waitcnt vmcnt(" #VM ")" ::: "memory");                    \
    __builtin_amdgcn_s_barrier();                                             \
    asm volatile("s_waitcnt lgkmcnt(0)" ::: "memory");                        \
    __builtin_amdgcn_sched_barrier(0);                                        \
    __builtin_amdgcn_s_setprio(1);                                            \
    _Pragma("unroll")                                                         \
    for (int m = 0; m < 4; ++m)                                               \
      _Pragma("unroll")                                                       \
      for (int n = 0; n < 2; ++n)                                             \
        acc[m][n] = __builtin_amdgcn_mfma_f32_32x32x16_bf16(af_[m], bf_[n], acc[m][n], 0, 0, 0); \
    __builtin_amdgcn_s_setprio(0);                                            \
    __builtin_amdgcn_s_barrier();                                             \
  } while (0)

  for (int u = 0; u < NU - 3; ++u) {   // u = 0..52, stages tile u+3
    if (s0 && u == 32) {               // base GEMM complete -> silu in registers
      #pragma unroll
      for (int m = 0; m < 4; ++m)
        #pragma unroll
        for (int n = 0; n < 2; ++n)
          #pragma unroll
          for (int j = 0; j < 16; ++j) {
            float v = acc[m][n][j];
            acc[m][n][j] = v / (1.0f + __expf(-v));
          }
    }
    PH0(u, true);
    PH1(u, true, 8);
  }
  PH0(53, false); PH1(53, false, 4);
  PH0(54, false); PH1(54, false, 0);
  PH0(55, false); PH1(55, false, 0);
#undef PH0
#undef PH1

  // C/D layout (32x32, measured m74/m101): col = lane&31,
  // row = (reg&3) + 8*(reg>>2) + 4*(lane>>5)
  float* dst = s0 ? out : (P + (size_t)(split - 1) * ((size_t)B_ROWS * O_DIM));
  #pragma unroll
  for (int m = 0; m < 4; ++m)
    #pragma unroll
    for (int n = 0; n < 2; ++n) {
      const size_t rb = brow + wm * 128 + m * 32 + 4 * hi;
      const size_t c  = bcol + wn * 64 + n * 32 + lr;
      #pragma unroll
      for (int j = 0; j < 16; ++j) {
        const size_t r = rb + (j & 3) + 8 * (j >> 2);
        dst[r * O_DIM + c] = acc[m][n][j];
      }
    }
}

// ---- final: out += P0 + P1 + P2 (float4) ----
__global__ void k_reduce(float* __restrict__ out, const float* __restrict__ P) {
  const size_t i = (size_t)blockIdx.x * 256 + threadIdx.x;
  const size_t NE = (size_t)B_ROWS * O_DIM / 4;
  float4 a = ((const float4*)out)[i];
  float4 b = ((const float4*)P)[i];
  float4 c = ((const float4*)P)[i + NE];
  float4 d = ((const float4*)P)[i + 2 * NE];
  a.x += b.x + c.x + d.x;  a.y += b.y + c.y + d.y;
  a.z += b.z + c.z + d.z;  a.w += b.w + c.w + d.w;
  ((float4*)out)[i] = a;
}

extern "C" void kernel_launch(void* const* d_in, const int* in_sizes, int n_in,
                              void* d_out, int out_size, void* d_ws, size_t ws_size,
                              hipStream_t stream) {
  const float* x  = (const float*)d_in[0];   // [4096][1024]
  const float* bw = (const float*)d_in[1];   // [1024][1024]
  const float* lw = (const float*)d_in[2];   // [1024][1024][6]
  float* out = (float*)d_out;                // [4096][1024]

  char* w = (char*)d_ws;
  u16*  Ab = (u16*)(w);                                  //  8 MiB [4096][1024]
  u16*  Al = (u16*)(w + (size_t)8   * 1024 * 1024);      // 48 MiB [4096][6144]
  u16*  Bb = (u16*)(w + (size_t)56  * 1024 * 1024);      //  2 MiB [1024][1024]
  u16*  Bl = (u16*)(w + (size_t)58  * 1024 * 1024);      // 12 MiB [1024][6144]
  float* P = (float*)(w + (size_t)72 * 1024 * 1024);     // 48 MiB: 3 x [4096][1024] f32

  hipFuncSetAttribute((const void*)k_gemm,
                      hipFuncAttributeMaxDynamicSharedMemorySize, LDS_BYTES);

  k_prep_w    <<<dim3(2048), 256, 0, stream>>>(bw, lw, Bb, Bl);
  k_prep_basis<<<dim3(B_ROWS), 256, 0, stream>>>(x, Ab, Al);
  k_gemm      <<<dim3(4 * (B_ROWS / BM) * (O_DIM / BN)), 512, LDS_BYTES, stream>>>(Ab, Bb, Al, Bl, out, P);
  k_reduce    <<<dim3((B_ROWS * O_DIM / 4) / 256), 256, 0, stream>>>(out, P);
}

// Round 8
// 114.864 us; speedup vs baseline: 1.0282x; 1.0282x over previous
//
#include <hip/hip_runtime.h>
#include <stdint.h>

typedef unsigned short u16;
typedef unsigned int   u32;
typedef __attribute__((ext_vector_type(8)))  short bhalf8;   // 8 bf16 = 4 VGPRs
typedef __attribute__((ext_vector_type(16))) float f32x16;

#define B_ROWS 4096
#define I_DIM  1024
#define O_DIM  1024
#define N_D    6
#define K_LEG  (I_DIM * N_D)   /* 6144 */

#define BM 256
#define BN 256
#define BK 32
#define NU 56                   /* K-tiles per split (224 total / 4 splits) */
#define SLOT_BYTES 32768        /* A 16KB + B 16KB */
#define LDS_BYTES  131072       /* 4-slot ring */

// float -> bf16 round-to-nearest-even
__device__ __forceinline__ u16 f2b(float f) {
  u32 u = __float_as_uint(f);
  return (u16)((u + 0x7fffu + ((u >> 16) & 1u)) >> 16);
}

// async global->LDS, 16B per lane; LDS dest = wave-uniform base + lane*16
__device__ __forceinline__ void gld_lds16(const void* g, void* l) {
  __builtin_amdgcn_global_load_lds(
      (const __attribute__((address_space(1))) u32*)(uintptr_t)g,
      (__attribute__((address_space(3))) u32*)(u32)(uintptr_t)l, 16, 0, 0);
}

// ---- prep (merged): blocks [0,1024): Bb[o][i] = bf16(bw[i][o]) via 32x32 LDS tile
//                     blocks [1024,2048): Bl[o][i*6+d] = bf16(lw[i][o][d]) ----
#define RS 201
__global__ void k_prep_w(const float* __restrict__ bw, const float* __restrict__ lw,
                         u16* __restrict__ Bb, u16* __restrict__ Bl) {
  __shared__ float t[32 * RS];
  if (blockIdx.x < 1024) {
    const int bx = blockIdx.x & 31, by = blockIdx.x >> 5;
    const int i0 = by * 32, o0 = bx * 32;
    const int c = threadIdx.x & 31, r0 = threadIdx.x >> 5;
    #pragma unroll
    for (int k = 0; k < 4; ++k) {
      int r = r0 + k * 8;
      t[r * 33 + c] = bw[(size_t)(i0 + r) * O_DIM + o0 + c];
    }
    __syncthreads();
    #pragma unroll
    for (int k = 0; k < 4; ++k) {
      int r = r0 + k * 8;
      Bb[(size_t)(o0 + r) * I_DIM + i0 + c] = f2b(t[c * 33 + r]);
    }
  } else {
    const int blk = blockIdx.x - 1024;
    const int bx = blk & 31, by = blk >> 5;
    const int i0 = by * 32, o0 = bx * 32;
    for (int q = threadIdx.x; q < 32 * 48; q += 256) {
      int ri = q / 48, s4 = q % 48;
      float4 v = *(const float4*)(lw + (size_t)(i0 + ri) * (O_DIM * N_D) + o0 * N_D + s4 * 4);
      float* p = t + ri * RS + s4 * 4;
      p[0] = v.x; p[1] = v.y; p[2] = v.z; p[3] = v.w;
    }
    __syncthreads();
    for (int q = threadIdx.x; q < 32 * 96; q += 256) {
      int ro = q / 96, k = q % 96;
      int e0 = 2 * k, e1 = 2 * k + 1;
      float v0 = t[(e0 / 6) * RS + ro * 6 + (e0 % 6)];
      float v1 = t[(e1 / 6) * RS + ro * 6 + (e1 % 6)];
      u32* dst = (u32*)(Bl + (size_t)(o0 + ro) * K_LEG + i0 * N_D);
      dst[k] = (u32)f2b(v0) | ((u32)f2b(v1) << 16);
    }
  }
}

// ---- prep: per-row min/max, Legendre basis, x*P_d -> bf16 ----
__global__ void k_prep_basis(const float* __restrict__ x,
                             u16* __restrict__ Ab, u16* __restrict__ Al) {
  int b = blockIdx.x;
  int t = threadIdx.x;    // 256 threads, 4 elems each
  float4 v = ((const float4*)(x + (size_t)b * I_DIM))[t];
  float mn = fminf(fminf(v.x, v.y), fminf(v.z, v.w));
  float mx = fmaxf(fmaxf(v.x, v.y), fmaxf(v.z, v.w));
  #pragma unroll
  for (int off = 32; off > 0; off >>= 1) {
    mn = fminf(mn, __shfl_xor(mn, off, 64));
    mx = fmaxf(mx, __shfl_xor(mx, off, 64));
  }
  __shared__ float smn[4], smx[4];
  if ((t & 63) == 0) { smn[t >> 6] = mn; smx[t >> 6] = mx; }
  __syncthreads();
  mn = fminf(fminf(smn[0], smn[1]), fminf(smn[2], smn[3]));
  mx = fmaxf(fmaxf(smx[0], smx[1]), fmaxf(smx[2], smx[3]));
  float sc = 2.0f / (mx - mn + 1e-7f);

  float xs[4] = {v.x, v.y, v.z, v.w};
  u32 lb[12];
  #pragma unroll
  for (int e = 0; e < 4; ++e) {
    float xv = xs[e];
    float xn = (xv - mn) * sc - 1.0f;
    float p0 = 1.0f, p1 = xn;
    float p2 = (3.0f * xn * p1 - 1.0f * p0) * (1.0f / 2.0f);
    float p3 = (5.0f * xn * p2 - 2.0f * p1) * (1.0f / 3.0f);
    float p4 = (7.0f * xn * p3 - 3.0f * p2) * (1.0f / 4.0f);
    float p5 = (9.0f * xn * p4 - 4.0f * p3) * (1.0f / 5.0f);
    lb[e * 3 + 0] = (u32)f2b(xv * p0) | ((u32)f2b(xv * p1) << 16);
    lb[e * 3 + 1] = (u32)f2b(xv * p2) | ((u32)f2b(xv * p3) << 16);
    lb[e * 3 + 2] = (u32)f2b(xv * p4) | ((u32)f2b(xv * p5) << 16);
  }
  u32 a0 = (u32)f2b(xs[0]) | ((u32)f2b(xs[1]) << 16);
  u32 a1 = (u32)f2b(xs[2]) | ((u32)f2b(xs[3]) << 16);
  *(uint2*)(Ab + (size_t)b * I_DIM + t * 4) = make_uint2(a0, a1);
  uint4* dl = (uint4*)(Al + (size_t)b * K_LEG + t * 24);
  dl[0] = make_uint4(lb[0], lb[1], lb[2], lb[3]);
  dl[1] = make_uint4(lb[4], lb[5], lb[6], lb[7]);
  dl[2] = make_uint4(lb[8], lb[9], lb[10], lb[11]);
}

// ---- fused split-K=4 GEMM: 256x256, 8 waves, 32x32x16 MFMA, 4-slot ring,
//      reg-double-buffered K-subtile pipeline (1 barrier/tile) ----
// split 0: base(32 K-tiles) -> silu(acc) -> leg [0,24) -> store to out
// splits 1..3: leg [24+56(s-1), 24+56s)  -> store to P[s-1]
__global__ __launch_bounds__(512, 2) void k_gemm(
    const u16* __restrict__ Ab, const u16* __restrict__ Bb,
    const u16* __restrict__ Al, const u16* __restrict__ Bl,
    float* __restrict__ out, float* __restrict__ P) {
  extern __shared__ char lds[];

  const int tid  = threadIdx.x;
  const int wave = tid >> 6;
  const int lane = tid & 63;
  const int wm = wave >> 2;            // 0..1: 128-row band
  const int wn = wave & 3;             // 0..3: 64-col band
  const u32 lr = lane & 31;            // 32x32 frag row/col
  const u32 hi = (u32)lane >> 5;       // k half: k = hi*8 + j

  const int bid   = blockIdx.x;        // 256 blocks = 1/CU
  const int bx    = bid >> 4;          // 0..15
  const int by    = (bid >> 2) & 3;    // 0..3
  const int split = bid & 3;
  const size_t brow = (size_t)bx * BM;
  const size_t bcol = (size_t)by * BN;
  const bool s0 = (split == 0);
  const int legbase = s0 ? 0 : (24 + 56 * (split - 1));

  // staging: thread t covers (row = r4, chunk-pos = t&3) of each 128-row half;
  // source chunk pre-swizzled: g = pos ^ key(row), key(r) = ((r>>1)&3)^((r>>3)&3)
  const int r4 = tid >> 2;
  const u32 skey = (((u32)r4 >> 1) & 3) ^ (((u32)r4 >> 3) & 3);
  const size_t cs = (size_t)(((u32)(tid & 3) ^ skey) * 8);
  char* const l0 = lds + (u32)wave * 1024;

  // incremental staging pointers (reset once at base->leg boundary)
  const u16 *gA0, *gA1, *gB0, *gB1;
  auto set_ptrs = [&](const u16* A, const u16* Bt, size_t ldk, size_t kt) {
    const size_t ko = kt * BK + cs;
    gA0 = A  + (brow + r4) * ldk + ko;
    gA1 = A  + (brow + 128 + r4) * ldk + ko;
    gB0 = Bt + (bcol + r4) * ldk + ko;
    gB1 = Bt + (bcol + 128 + r4) * ldk + ko;
  };
  if (s0) set_ptrs(Ab, Bb, I_DIM, 0);
  else    set_ptrs(Al, Bl, K_LEG, (size_t)legbase);

  auto stage = [&](int v) {
    if (s0 && v == 32) set_ptrs(Al, Bl, K_LEG, 0);
    char* d = l0 + (size_t)(v & 3) * SLOT_BYTES;
    gld_lds16(gA0, d);          gld_lds16(gA1, d + 8192);
    gld_lds16(gB0, d + 16384);  gld_lds16(gB1, d + 24576);
    gA0 += BK; gA1 += BK; gB0 += BK; gB1 += BK;
  };

  // frag-read byte offsets: chunk (kk*2+hi) stored at (kk*2+hi)^key(row);
  // key(row) reduces to per-lane const ((lr>>1)&3)^((lr>>3)&3) for all frags
  const u32 key = ((lr >> 1) & 3) ^ ((lr >> 3) & 3);
  const u32 c00 = ((0 + hi) ^ key) * 16;   // kk = 0
  const u32 c10 = ((2 + hi) ^ key) * 16;   // kk = 1
  const u32 abase_r = (u32)wm * 8192 + lr * 64;
  const u32 bbase_r = 16384u + ((u32)wn >> 1) * 8192 + ((u32)wn & 1) * 4096 + lr * 64;

  f32x16 acc[4][2] = {};
  bhalf8 af0[4], bf0[2], af1[4], bf1[2];

  // prologue: stage tiles 0,1; confirm tile 0; preload setA = kk0(0)
  stage(0); stage(1);
  asm volatile("s_waitcnt vmcnt(4)" ::: "memory");
  __builtin_amdgcn_s_barrier();
  {
    const char* p = lds;
    #pragma unroll
    for (int n = 0; n < 2; ++n) bf0[n] = *(const bhalf8*)(p + bbase_r + n * 2048 + c00);
    #pragma unroll
    for (int m = 0; m < 4; ++m) af0[m] = *(const bhalf8*)(p + abase_r + m * 2048 + c00);
  }

  for (int u = 0; u < NU; ++u) {
    if (s0 && u == 32) {               // base GEMM complete -> silu in registers
      #pragma unroll
      for (int m = 0; m < 4; ++m)
        #pragma unroll
        for (int n = 0; n < 2; ++n)
          #pragma unroll
          for (int j = 0; j < 16; ++j) {
            float v = acc[m][n][j];
            acc[m][n][j] = v / (1.0f + __expf(-v));
          }
    }
    if (u < NU - 2) {
      stage(u + 2);
      asm volatile("s_waitcnt vmcnt(4)" ::: "memory");   // tile u+1 landed (own)
    } else {
      asm volatile("s_waitcnt vmcnt(0)" ::: "memory");
    }
    __builtin_amdgcn_s_barrier();                         // all waves' u+1 landed
    asm volatile("s_waitcnt lgkmcnt(0)" ::: "memory");    // setA (kk0(u)) ready
    __builtin_amdgcn_sched_barrier(0);

    const char* p = lds + (size_t)(u & 3) * SLOT_BYTES;
    #pragma unroll
    for (int n = 0; n < 2; ++n) bf1[n] = *(const bhalf8*)(p + bbase_r + n * 2048 + c10);
    #pragma unroll
    for (int m = 0; m < 4; ++m) af1[m] = *(const bhalf8*)(p + abase_r + m * 2048 + c10);
    __builtin_amdgcn_sched_barrier(0);

    __builtin_amdgcn_s_setprio(1);                        // MFMA kk0 overlaps setB reads
    #pragma unroll
    for (int m = 0; m < 4; ++m)
      #pragma unroll
      for (int n = 0; n < 2; ++n)
        acc[m][n] = __builtin_amdgcn_mfma_f32_32x32x16_bf16(af0[m], bf0[n], acc[m][n], 0, 0, 0);
    __builtin_amdgcn_s_setprio(0);

    asm volatile("s_waitcnt lgkmcnt(0)" ::: "memory");    // setB (kk1(u)) ready
    __builtin_amdgcn_sched_barrier(0);
    if (u < NU - 1) {                                     // setA = kk0(u+1), slot landed
      const char* pn = lds + (size_t)((u + 1) & 3) * SLOT_BYTES;
      #pragma unroll
      for (int n = 0; n < 2; ++n) bf0[n] = *(const bhalf8*)(pn + bbase_r + n * 2048 + c00);
      #pragma unroll
      for (int m = 0; m < 4; ++m) af0[m] = *(const bhalf8*)(pn + abase_r + m * 2048 + c00);
    }
    __builtin_amdgcn_sched_barrier(0);

    __builtin_amdgcn_s_setprio(1);                        // MFMA kk1 overlaps setA reads
    #pragma unroll
    for (int m = 0; m < 4; ++m)
      #pragma unroll
      for (int n = 0; n < 2; ++n)
        acc[m][n] = __builtin_amdgcn_mfma_f32_32x32x16_bf16(af1[m], bf1[n], acc[m][n], 0, 0, 0);
    __builtin_amdgcn_s_setprio(0);
  }

  // C/D layout (32x32, measured m74/m101): col = lane&31,
  // row = (reg&3) + 8*(reg>>2) + 4*(lane>>5)
  float* dst = s0 ? out : (P + (size_t)(split - 1) * ((size_t)B_ROWS * O_DIM));
  #pragma unroll
  for (int m = 0; m < 4; ++m)
    #pragma unroll
    for (int n = 0; n < 2; ++n) {
      const size_t rb = brow + wm * 128 + m * 32 + 4 * hi;
      const size_t c  = bcol + wn * 64 + n * 32 + lr;
      #pragma unroll
      for (int j = 0; j < 16; ++j) {
        const size_t r = rb + (j & 3) + 8 * (j >> 2);
        dst[r * O_DIM + c] = acc[m][n][j];
      }
    }
}

// ---- final: out += P0 + P1 + P2 (float4) ----
__global__ void k_reduce(float* __restrict__ out, const float* __restrict__ P) {
  const size_t i = (size_t)blockIdx.x * 256 + threadIdx.x;
  const size_t NE = (size_t)B_ROWS * O_DIM / 4;
  float4 a = ((const float4*)out)[i];
  float4 b = ((const float4*)P)[i];
  float4 c = ((const float4*)P)[i + NE];
  float4 d = ((const float4*)P)[i + 2 * NE];
  a.x += b.x + c.x + d.x;  a.y += b.y + c.y + d.y;
  a.z += b.z + c.z + d.z;  a.w += b.w + c.w + d.w;
  ((float4*)out)[i] = a;
}

extern "C" void kernel_launch(void* const* d_in, const int* in_sizes, int n_in,
                              void* d_out, int out_size, void* d_ws, size_t ws_size,
                              hipStream_t stream) {
  const float* x  = (const float*)d_in[0];   // [4096][1024]
  const float* bw = (const float*)d_in[1];   // [1024][1024]
  const float* lw = (const float*)d_in[2];   // [1024][1024][6]
  float* out = (float*)d_out;                // [4096][1024]

  char* w = (char*)d_ws;
  u16*  Ab = (u16*)(w);                                  //  8 MiB [4096][1024]
  u16*  Al = (u16*)(w + (size_t)8   * 1024 * 1024);      // 48 MiB [4096][6144]
  u16*  Bb = (u16*)(w + (size_t)56  * 1024 * 1024);      //  2 MiB [1024][1024]
  u16*  Bl = (u16*)(w + (size_t)58  * 1024 * 1024);      // 12 MiB [1024][6144]
  float* P = (float*)(w + (size_t)72 * 1024 * 1024);     // 48 MiB: 3 x [4096][1024] f32

  hipFuncSetAttribute((const void*)k_gemm,
                      hipFuncAttributeMaxDynamicSharedMemorySize, LDS_BYTES);

  k_prep_w    <<<dim3(2048), 256, 0, stream>>>(bw, lw, Bb, Bl);
  k_prep_basis<<<dim3(B_ROWS), 256, 0, stream>>>(x, Ab, Al);
  k_gemm      <<<dim3(4 * (B_ROWS / BM) * (O_DIM / BN)), 512, LDS_BYTES, stream>>>(Ab, Bb, Al, Bl, out, P);
  k_reduce    <<<dim3((B_ROWS * O_DIM / 4) / 256), 256, 0, stream>>>(out, P);
}

// Round 9
// 114.101 us; speedup vs baseline: 1.0351x; 1.0067x over previous
//
#include <hip/hip_runtime.h>
#include <stdint.h>

typedef unsigned short u16;
typedef unsigned int   u32;
typedef __attribute__((ext_vector_type(8)))  short bhalf8;   // 8 bf16 = 4 VGPRs
typedef __attribute__((ext_vector_type(16))) float f32x16;

#define B_ROWS 4096
#define I_DIM  1024
#define O_DIM  1024
#define N_D    6
#define K_LEG  (I_DIM * N_D)   /* 6144 */

#define BM 256
#define BN 256
#define BK 32
#define NU 56                   /* K-tiles per split (224 total / 4 splits) */
#define SLOT_BYTES 32768        /* A 16KB + B 16KB */
#define LDS_BYTES  131072       /* 4-slot ring */

// float -> bf16 round-to-nearest-even
__device__ __forceinline__ u16 f2b(float f) {
  u32 u = __float_as_uint(f);
  return (u16)((u + 0x7fffu + ((u >> 16) & 1u)) >> 16);
}

// async global->LDS, 16B per lane; LDS dest = wave-uniform base + lane*16
__device__ __forceinline__ void gld_lds16(const void* g, void* l) {
  __builtin_amdgcn_global_load_lds(
      (const __attribute__((address_space(1))) u32*)(uintptr_t)g,
      (__attribute__((address_space(3))) u32*)(u32)(uintptr_t)l, 16, 0, 0);
}

// ---- prep (merged): blocks [0,1024): Bb[o][i] = bf16(bw[i][o]) via 32x32 LDS tile
//                     blocks [1024,2048): Bl[o][i*6+d] = bf16(lw[i][o][d]) ----
#define RS 201
__global__ void k_prep_w(const float* __restrict__ bw, const float* __restrict__ lw,
                         u16* __restrict__ Bb, u16* __restrict__ Bl) {
  __shared__ float t[32 * RS];
  if (blockIdx.x < 1024) {
    const int bx = blockIdx.x & 31, by = blockIdx.x >> 5;
    const int i0 = by * 32, o0 = bx * 32;
    const int c = threadIdx.x & 31, r0 = threadIdx.x >> 5;
    #pragma unroll
    for (int k = 0; k < 4; ++k) {
      int r = r0 + k * 8;
      t[r * 33 + c] = bw[(size_t)(i0 + r) * O_DIM + o0 + c];
    }
    __syncthreads();
    #pragma unroll
    for (int k = 0; k < 4; ++k) {
      int r = r0 + k * 8;
      Bb[(size_t)(o0 + r) * I_DIM + i0 + c] = f2b(t[c * 33 + r]);
    }
  } else {
    const int blk = blockIdx.x - 1024;
    const int bx = blk & 31, by = blk >> 5;
    const int i0 = by * 32, o0 = bx * 32;
    for (int q = threadIdx.x; q < 32 * 48; q += 256) {
      int ri = q / 48, s4 = q % 48;
      float4 v = *(const float4*)(lw + (size_t)(i0 + ri) * (O_DIM * N_D) + o0 * N_D + s4 * 4);
      float* p = t + ri * RS + s4 * 4;
      p[0] = v.x; p[1] = v.y; p[2] = v.z; p[3] = v.w;
    }
    __syncthreads();
    for (int q = threadIdx.x; q < 32 * 96; q += 256) {
      int ro = q / 96, k = q % 96;
      int e0 = 2 * k, e1 = 2 * k + 1;
      float v0 = t[(e0 / 6) * RS + ro * 6 + (e0 % 6)];
      float v1 = t[(e1 / 6) * RS + ro * 6 + (e1 % 6)];
      u32* dst = (u32*)(Bl + (size_t)(o0 + ro) * K_LEG + i0 * N_D);
      dst[k] = (u32)f2b(v0) | ((u32)f2b(v1) << 16);
    }
  }
}

// ---- prep: per-row min/max, Legendre basis, x*P_d -> bf16 ----
__global__ void k_prep_basis(const float* __restrict__ x,
                             u16* __restrict__ Ab, u16* __restrict__ Al) {
  int b = blockIdx.x;
  int t = threadIdx.x;    // 256 threads, 4 elems each
  float4 v = ((const float4*)(x + (size_t)b * I_DIM))[t];
  float mn = fminf(fminf(v.x, v.y), fminf(v.z, v.w));
  float mx = fmaxf(fmaxf(v.x, v.y), fmaxf(v.z, v.w));
  #pragma unroll
  for (int off = 32; off > 0; off >>= 1) {
    mn = fminf(mn, __shfl_xor(mn, off, 64));
    mx = fmaxf(mx, __shfl_xor(mx, off, 64));
  }
  __shared__ float smn[4], smx[4];
  if ((t & 63) == 0) { smn[t >> 6] = mn; smx[t >> 6] = mx; }
  __syncthreads();
  mn = fminf(fminf(smn[0], smn[1]), fminf(smn[2], smn[3]));
  mx = fmaxf(fmaxf(smx[0], smx[1]), fmaxf(smx[2], smx[3]));
  float sc = 2.0f / (mx - mn + 1e-7f);

  float xs[4] = {v.x, v.y, v.z, v.w};
  u32 lb[12];
  #pragma unroll
  for (int e = 0; e < 4; ++e) {
    float xv = xs[e];
    float xn = (xv - mn) * sc - 1.0f;
    float p0 = 1.0f, p1 = xn;
    float p2 = (3.0f * xn * p1 - 1.0f * p0) * (1.0f / 2.0f);
    float p3 = (5.0f * xn * p2 - 2.0f * p1) * (1.0f / 3.0f);
    float p4 = (7.0f * xn * p3 - 3.0f * p2) * (1.0f / 4.0f);
    float p5 = (9.0f * xn * p4 - 4.0f * p3) * (1.0f / 5.0f);
    lb[e * 3 + 0] = (u32)f2b(xv * p0) | ((u32)f2b(xv * p1) << 16);
    lb[e * 3 + 1] = (u32)f2b(xv * p2) | ((u32)f2b(xv * p3) << 16);
    lb[e * 3 + 2] = (u32)f2b(xv * p4) | ((u32)f2b(xv * p5) << 16);
  }
  u32 a0 = (u32)f2b(xs[0]) | ((u32)f2b(xs[1]) << 16);
  u32 a1 = (u32)f2b(xs[2]) | ((u32)f2b(xs[3]) << 16);
  *(uint2*)(Ab + (size_t)b * I_DIM + t * 4) = make_uint2(a0, a1);
  uint4* dl = (uint4*)(Al + (size_t)b * K_LEG + t * 24);
  dl[0] = make_uint4(lb[0], lb[1], lb[2], lb[3]);
  dl[1] = make_uint4(lb[4], lb[5], lb[6], lb[7]);
  dl[2] = make_uint4(lb[8], lb[9], lb[10], lb[11]);
}

// ---- fused split-K=4 GEMM: 256x256, 8 waves, 32x32x16 MFMA, 4-slot ring,
//      3-set rotating reg pipeline: frags prefetched one FULL tile ahead,
//      compiler-counted lgkm waits (never 0 in loop), 1 barrier/tile ----
__global__ __launch_bounds__(512, 2) void k_gemm(
    const u16* __restrict__ Ab, const u16* __restrict__ Bb,
    const u16* __restrict__ Al, const u16* __restrict__ Bl,
    float* __restrict__ out, float* __restrict__ P) {
  extern __shared__ char lds[];

  const int tid  = threadIdx.x;
  const int wave = tid >> 6;
  const int lane = tid & 63;
  const int wm = wave >> 2;            // 0..1: 128-row band
  const int wn = wave & 3;             // 0..3: 64-col band
  const u32 lr = lane & 31;            // 32x32 frag row/col
  const u32 hi = (u32)lane >> 5;       // k half: k = hi*8 + j

  const int bid   = blockIdx.x;        // 256 blocks = 1/CU
  const int bx    = bid >> 4;          // 0..15
  const int by    = (bid >> 2) & 3;    // 0..3
  const int split = bid & 3;
  const size_t brow = (size_t)bx * BM;
  const size_t bcol = (size_t)by * BN;
  const bool s0 = (split == 0);
  const int legbase = s0 ? 0 : (24 + 56 * (split - 1));

  // staging: thread t covers (row = r4, chunk-pos = t&3) of each 128-row half;
  // source chunk pre-swizzled: g = pos ^ key(row), key(r) = ((r>>1)&3)^((r>>3)&3)
  const int r4 = tid >> 2;
  const u32 skey = (((u32)r4 >> 1) & 3) ^ (((u32)r4 >> 3) & 3);
  const size_t cs = (size_t)(((u32)(tid & 3) ^ skey) * 8);
  char* const l0 = lds + (u32)wave * 1024;

  const u16 *gA0, *gA1, *gB0, *gB1;
  auto set_ptrs = [&](const u16* A, const u16* Bt, size_t ldk, size_t kt) {
    const size_t ko = kt * BK + cs;
    gA0 = A  + (brow + r4) * ldk + ko;
    gA1 = A  + (brow + 128 + r4) * ldk + ko;
    gB0 = Bt + (bcol + r4) * ldk + ko;
    gB1 = Bt + (bcol + 128 + r4) * ldk + ko;
  };
  if (s0) set_ptrs(Ab, Bb, I_DIM, 0);
  else    set_ptrs(Al, Bl, K_LEG, (size_t)legbase);

  auto stage = [&](int v) {
    if (s0 && v == 32) set_ptrs(Al, Bl, K_LEG, 0);
    char* d = l0 + (size_t)(v & 3) * SLOT_BYTES;
    gld_lds16(gA0, d);          gld_lds16(gA1, d + 8192);
    gld_lds16(gB0, d + 16384);  gld_lds16(gB1, d + 24576);
    gA0 += BK; gA1 += BK; gB0 += BK; gB1 += BK;
  };

  // frag-read offsets: chunk (kk*2+hi) stored at (kk*2+hi)^key(row)
  const u32 key = ((lr >> 1) & 3) ^ ((lr >> 3) & 3);
  const u32 c00 = ((0 + hi) ^ key) * 16;   // kk = 0
  const u32 c10 = ((2 + hi) ^ key) * 16;   // kk = 1
  const u32 abase_r = (u32)wm * 8192 + lr * 64;
  const u32 bbase_r = 16384u + ((u32)wn >> 1) * 8192 + ((u32)wn & 1) * 4096 + lr * 64;

  f32x16 acc[4][2] = {};
  bhalf8 a0[4], b0[2], a1[4], b1[2], a2[4], b2[2];   // 3 rotating operand sets

  auto silu = [&]() {
    #pragma unroll
    for (int m = 0; m < 4; ++m)
      #pragma unroll
      for (int n = 0; n < 2; ++n)
        #pragma unroll
        for (int j = 0; j < 16; ++j) {
          float v = acc[m][n][j];
          acc[m][n][j] = v / (1.0f + __expf(-v));
        }
  };

#define FILL(u1, CH, AA, BB) do {                                             \
    const char* pn_ = lds + (size_t)((u1) & 3) * SLOT_BYTES;                  \
    BB[0] = *(const bhalf8*)(pn_ + bbase_r + (CH));                           \
    BB[1] = *(const bhalf8*)(pn_ + bbase_r + 2048 + (CH));                    \
    AA[0] = *(const bhalf8*)(pn_ + abase_r + (CH));                           \
    AA[1] = *(const bhalf8*)(pn_ + abase_r + 2048 + (CH));                    \
    AA[2] = *(const bhalf8*)(pn_ + abase_r + 4096 + (CH));                    \
    AA[3] = *(const bhalf8*)(pn_ + abase_r + 6144 + (CH));                    \
  } while (0)

#define MM(AA, BB) do {                                                       \
    __builtin_amdgcn_sched_barrier(0);                                        \
    __builtin_amdgcn_s_setprio(1);                                            \
    _Pragma("unroll")                                                         \
    for (int m = 0; m < 4; ++m)                                               \
      _Pragma("unroll")                                                       \
      for (int n = 0; n < 2; ++n)                                             \
        acc[m][n] = __builtin_amdgcn_mfma_f32_32x32x16_bf16(AA[m], BB[n], acc[m][n], 0, 0, 0); \
    __builtin_amdgcn_s_setprio(0);                                            \
    __builtin_amdgcn_sched_barrier(0);                                        \
  } while (0)

  // TILE(u): consume sets P (kk0) and Q (kk1); fill R <- kk0(u+1), P <- kk1(u+1)
#define TILE(u, PA, PB, QA, QB, RA, RB) do {                                  \
    const int u_ = (u);                                                       \
    if (s0 && u_ == 32) silu();                                               \
    if (u_ <= NU - 3) {                                                       \
      stage(u_ + 2);                                                          \
      asm volatile("s_waitcnt vmcnt(4)" ::: "memory");  /* tile u+1 landed */ \
    } else {                                                                  \
      asm volatile("s_waitcnt vmcnt(0)" ::: "memory");                        \
    }                                                                         \
    __builtin_amdgcn_s_barrier();                                             \
    if (u_ < NU - 1) FILL(u_ + 1, c00, RA, RB);                               \
    MM(PA, PB);                                                               \
    if (u_ < NU - 1) FILL(u_ + 1, c10, PA, PB);                               \
    MM(QA, QB);                                                               \
  } while (0)

  // prologue: stage tiles 0,1; confirm tile 0; fill both halves of tile 0
  stage(0); stage(1);
  asm volatile("s_waitcnt vmcnt(4)" ::: "memory");
  __builtin_amdgcn_s_barrier();
  FILL(0, c00, a0, b0);
  FILL(0, c10, a1, b1);

  for (int t = 0; t < 18; ++t) {       // tiles 0..53
    const int u = t * 3;
    TILE(u,     a0, b0, a1, b1, a2, b2);
    TILE(u + 1, a2, b2, a0, b0, a1, b1);
    TILE(u + 2, a1, b1, a2, b2, a0, b0);
  }
  TILE(54, a0, b0, a1, b1, a2, b2);
  TILE(55, a2, b2, a0, b0, a1, b1);
#undef TILE
#undef MM
#undef FILL

  // C/D layout (32x32, measured m74/m101): col = lane&31,
  // row = (reg&3) + 8*(reg>>2) + 4*(lane>>5)
  float* dst = s0 ? out : (P + (size_t)(split - 1) * ((size_t)B_ROWS * O_DIM));
  #pragma unroll
  for (int m = 0; m < 4; ++m)
    #pragma unroll
    for (int n = 0; n < 2; ++n) {
      const size_t rb = brow + wm * 128 + m * 32 + 4 * hi;
      const size_t c  = bcol + wn * 64 + n * 32 + lr;
      #pragma unroll
      for (int j = 0; j < 16; ++j) {
        const size_t r = rb + (j & 3) + 8 * (j >> 2);
        dst[r * O_DIM + c] = acc[m][n][j];
      }
    }
}

// ---- final: out += P0 + P1 + P2 (float4) ----
__global__ void k_reduce(float* __restrict__ out, const float* __restrict__ P) {
  const size_t i = (size_t)blockIdx.x * 256 + threadIdx.x;
  const size_t NE = (size_t)B_ROWS * O_DIM / 4;
  float4 a = ((const float4*)out)[i];
  float4 b = ((const float4*)P)[i];
  float4 c = ((const float4*)P)[i + NE];
  float4 d = ((const float4*)P)[i + 2 * NE];
  a.x += b.x + c.x + d.x;  a.y += b.y + c.y + d.y;
  a.z += b.z + c.z + d.z;  a.w += b.w + c.w + d.w;
  ((float4*)out)[i] = a;
}

extern "C" void kernel_launch(void* const* d_in, const int* in_sizes, int n_in,
                              void* d_out, int out_size, void* d_ws, size_t ws_size,
                              hipStream_t stream) {
  const float* x  = (const float*)d_in[0];   // [4096][1024]
  const float* bw = (const float*)d_in[1];   // [1024][1024]
  const float* lw = (const float*)d_in[2];   // [1024][1024][6]
  float* out = (float*)d_out;                // [4096][1024]

  char* w = (char*)d_ws;
  u16*  Ab = (u16*)(w);                                  //  8 MiB [4096][1024]
  u16*  Al = (u16*)(w + (size_t)8   * 1024 * 1024);      // 48 MiB [4096][6144]
  u16*  Bb = (u16*)(w + (size_t)56  * 1024 * 1024);      //  2 MiB [1024][1024]
  u16*  Bl = (u16*)(w + (size_t)58  * 1024 * 1024);      // 12 MiB [1024][6144]
  float* P = (float*)(w + (size_t)72 * 1024 * 1024);     // 48 MiB: 3 x [4096][1024] f32

  hipFuncSetAttribute((const void*)k_gemm,
                      hipFuncAttributeMaxDynamicSharedMemorySize, LDS_BYTES);

  k_prep_w    <<<dim3(2048), 256, 0, stream>>>(bw, lw, Bb, Bl);
  k_prep_basis<<<dim3(B_ROWS), 256, 0, stream>>>(x, Ab, Al);
  k_gemm      <<<dim3(4 * (B_ROWS / BM) * (O_DIM / BN)), 512, LDS_BYTES, stream>>>(Ab, Bb, Al, Bl, out, P);
  k_reduce    <<<dim3((B_ROWS * O_DIM / 4) / 256), 256, 0, stream>>>(out, P);
}

// Round 10
// 108.506 us; speedup vs baseline: 1.0885x; 1.0516x over previous
//
#include <hip/hip_runtime.h>
#include <stdint.h>

typedef unsigned short u16;
typedef unsigned int   u32;
typedef __attribute__((ext_vector_type(8)))  short bhalf8;   // 8 bf16 = 4 VGPRs
typedef __attribute__((ext_vector_type(16))) float f32x16;

#define B_ROWS 4096
#define I_DIM  1024
#define O_DIM  1024
#define N_D    6
#define K_LEG  (I_DIM * N_D)   /* 6144 */

#define BM 256
#define BN 256
#define BK 64
#define NS 28                   /* BK64 K-steps per split (112 total / 4) */
#define BUF_BYTES 65536         /* A 32KB + B 32KB */
#define LDS_BYTES 131072        /* 2 buffers */

// float -> bf16 round-to-nearest-even
__device__ __forceinline__ u16 f2b(float f) {
  u32 u = __float_as_uint(f);
  return (u16)((u + 0x7fffu + ((u >> 16) & 1u)) >> 16);
}

// async global->LDS, 16B per lane; LDS dest = wave-uniform base + lane*16
__device__ __forceinline__ void gld_lds16(const void* g, void* l) {
  __builtin_amdgcn_global_load_lds(
      (const __attribute__((address_space(1))) u32*)(uintptr_t)g,
      (__attribute__((address_space(3))) u32*)(u32)(uintptr_t)l, 16, 0, 0);
}

// ---- prep (fully merged, one launch):
//  blocks [0,1024):    Bb[o][i] = bf16(bw[i][o]) via 32x32 LDS tile
//  blocks [1024,2048): Bl[o][i*6+d] = bf16(lw[i][o][d]) via LDS microvector tile
//  blocks [2048,6144): per-row min/max + Legendre basis -> Ab, Al
#define RS 201
__global__ void k_prep(const float* __restrict__ bw, const float* __restrict__ lw,
                       const float* __restrict__ x,
                       u16* __restrict__ Bb, u16* __restrict__ Bl,
                       u16* __restrict__ Ab, u16* __restrict__ Al) {
  __shared__ float t[32 * RS];
  if (blockIdx.x < 1024) {
    const int bx = blockIdx.x & 31, by = blockIdx.x >> 5;
    const int i0 = by * 32, o0 = bx * 32;
    const int c = threadIdx.x & 31, r0 = threadIdx.x >> 5;
    #pragma unroll
    for (int k = 0; k < 4; ++k) {
      int r = r0 + k * 8;
      t[r * 33 + c] = bw[(size_t)(i0 + r) * O_DIM + o0 + c];
    }
    __syncthreads();
    #pragma unroll
    for (int k = 0; k < 4; ++k) {
      int r = r0 + k * 8;
      Bb[(size_t)(o0 + r) * I_DIM + i0 + c] = f2b(t[c * 33 + r]);
    }
  } else if (blockIdx.x < 2048) {
    const int blk = blockIdx.x - 1024;
    const int bx = blk & 31, by = blk >> 5;
    const int i0 = by * 32, o0 = bx * 32;
    for (int q = threadIdx.x; q < 32 * 48; q += 256) {
      int ri = q / 48, s4 = q % 48;
      float4 v = *(const float4*)(lw + (size_t)(i0 + ri) * (O_DIM * N_D) + o0 * N_D + s4 * 4);
      float* p = t + ri * RS + s4 * 4;
      p[0] = v.x; p[1] = v.y; p[2] = v.z; p[3] = v.w;
    }
    __syncthreads();
    for (int q = threadIdx.x; q < 32 * 96; q += 256) {
      int ro = q / 96, k = q % 96;
      int e0 = 2 * k, e1 = 2 * k + 1;
      float v0 = t[(e0 / 6) * RS + ro * 6 + (e0 % 6)];
      float v1 = t[(e1 / 6) * RS + ro * 6 + (e1 % 6)];
      u32* dst = (u32*)(Bl + (size_t)(o0 + ro) * K_LEG + i0 * N_D);
      dst[k] = (u32)f2b(v0) | ((u32)f2b(v1) << 16);
    }
  } else {
    const int b = blockIdx.x - 2048;
    const int tt = threadIdx.x;
    float4 v = ((const float4*)(x + (size_t)b * I_DIM))[tt];
    float mn = fminf(fminf(v.x, v.y), fminf(v.z, v.w));
    float mx = fmaxf(fmaxf(v.x, v.y), fmaxf(v.z, v.w));
    #pragma unroll
    for (int off = 32; off > 0; off >>= 1) {
      mn = fminf(mn, __shfl_xor(mn, off, 64));
      mx = fmaxf(mx, __shfl_xor(mx, off, 64));
    }
    __shared__ float smn[4], smx[4];
    if ((tt & 63) == 0) { smn[tt >> 6] = mn; smx[tt >> 6] = mx; }
    __syncthreads();
    mn = fminf(fminf(smn[0], smn[1]), fminf(smn[2], smn[3]));
    mx = fmaxf(fmaxf(smx[0], smx[1]), fmaxf(smx[2], smx[3]));
    float sc = 2.0f / (mx - mn + 1e-7f);

    float xs[4] = {v.x, v.y, v.z, v.w};
    u32 lb[12];
    #pragma unroll
    for (int e = 0; e < 4; ++e) {
      float xv = xs[e];
      float xn = (xv - mn) * sc - 1.0f;
      float p0 = 1.0f, p1 = xn;
      float p2 = (3.0f * xn * p1 - 1.0f * p0) * (1.0f / 2.0f);
      float p3 = (5.0f * xn * p2 - 2.0f * p1) * (1.0f / 3.0f);
      float p4 = (7.0f * xn * p3 - 3.0f * p2) * (1.0f / 4.0f);
      float p5 = (9.0f * xn * p4 - 4.0f * p3) * (1.0f / 5.0f);
      lb[e * 3 + 0] = (u32)f2b(xv * p0) | ((u32)f2b(xv * p1) << 16);
      lb[e * 3 + 1] = (u32)f2b(xv * p2) | ((u32)f2b(xv * p3) << 16);
      lb[e * 3 + 2] = (u32)f2b(xv * p4) | ((u32)f2b(xv * p5) << 16);
    }
    u32 a0 = (u32)f2b(xs[0]) | ((u32)f2b(xs[1]) << 16);
    u32 a1 = (u32)f2b(xs[2]) | ((u32)f2b(xs[3]) << 16);
    *(uint2*)(Ab + (size_t)b * I_DIM + tt * 4) = make_uint2(a0, a1);
    uint4* dl = (uint4*)(Al + (size_t)b * K_LEG + tt * 24);
    dl[0] = make_uint4(lb[0], lb[1], lb[2], lb[3]);
    dl[1] = make_uint4(lb[4], lb[5], lb[6], lb[7]);
    dl[2] = make_uint4(lb[8], lb[9], lb[10], lb[11]);
  }
}

// ---- fused split-K=4 GEMM: 256x256, 8 waves, 32x32x16 MFMA, BK=64 steps,
//      2-buffer LDS; window u reads buf[u&1] while staging step u+1 into the
//      other buffer (disjoint -> barriers only at window ends). Fragment reads
//      pipelined one cluster ahead; r&7 chunk-XOR swizzle (8 lanes/chunk = min).
// split 0: base steps 0..15 -> silu(acc) -> leg steps [0,12)
// splits 1..3: leg steps [12+28(s-1), 12+28s)
__global__ __launch_bounds__(512, 2) void k_gemm(
    const u16* __restrict__ Ab, const u16* __restrict__ Bb,
    const u16* __restrict__ Al, const u16* __restrict__ Bl,
    float* __restrict__ out, float* __restrict__ P) {
  extern __shared__ char lds[];

  const int tid  = threadIdx.x;
  const int wave = tid >> 6;
  const int lane = tid & 63;
  const int wm = wave >> 2;            // 0..1: 128-row band
  const int wn = wave & 3;             // 0..3: 64-col band
  const u32 lr = (u32)lane & 31;       // 32x32 frag row/col
  const u32 hi = (u32)lane >> 5;       // k half within 16

  const int bid   = blockIdx.x;        // 256 blocks = 1/CU
  const int bx    = bid >> 4;
  const int by    = (bid >> 2) & 3;
  const int split = bid & 3;
  const size_t brow = (size_t)bx * BM;
  const size_t bcol = (size_t)by * BN;
  const bool s0 = (split == 0);
  const int legbase = s0 ? 0 : (12 + 28 * (split - 1));

  // staging: thread t covers (row rt, chunk-pos t&7) of a 64-row group;
  // source chunk pre-swizzled by row&7 (involution; LDS dest stays linear)
  const int rt = tid >> 3;                                   // 0..63
  const u32 ct = (((u32)tid & 7) ^ ((u32)rt & 7)) * 8;       // u16 offset in 64-col row

  // stage half-tile h (0,1 = A halves; 2,3 = B halves) of K-step v
  auto stage_half = [&](int v, int h) {
    char* dst = lds + (size_t)(v & 1) * BUF_BYTES + ((h >= 2) ? 32768 : 0)
              + (size_t)(h & 1) * 16384 + (size_t)tid * 16;
    const size_t rbase = ((h < 2) ? brow : bcol) + (size_t)(h & 1) * 128 + (size_t)rt;
    const u16* src0;
    size_t rstep;
    if (s0 && v < 16) {
      const u16* M = (h < 2) ? Ab : Bb;
      src0 = M + rbase * I_DIM + (size_t)v * BK + ct;
      rstep = (size_t)64 * I_DIM;
    } else {
      const int lv = s0 ? (v - 16) : (legbase + v);
      const u16* M = (h < 2) ? Al : Bl;
      src0 = M + rbase * K_LEG + (size_t)lv * BK + ct;
      rstep = (size_t)64 * K_LEG;
    }
    gld_lds16(src0, dst);
    gld_lds16(src0 + rstep, dst + 8192);
  };

  // frag reads: row r stores chunk c at pos c ^ (r&7); r&7 == lane&7 for all frags.
  // nominal chunk(kk) = kk*2 + hi  ->  byte off = ((hi^(lane&7))*16) ^ (kk*32)
  const u32 c0off = (hi ^ ((u32)lane & 7)) * 16;
  const u32 abase = ((u32)wm * 128 + lr) * 128;
  const u32 bbase = 32768u + ((u32)wn * 64 + lr) * 128;

  f32x16 acc[4][2] = {};
  bhalf8 afa[4], bfa[2], afb[4], bfb[2];   // two named operand sets (rule #20)

#define READF(AF, BF, P_, KK) do {                                            \
    const u32 co_ = c0off ^ ((KK) << 5);                                      \
    BF[0] = *(const bhalf8*)((P_) + bbase + co_);                             \
    BF[1] = *(const bhalf8*)((P_) + bbase + 4096 + co_);                      \
    AF[0] = *(const bhalf8*)((P_) + abase + co_);                             \
    AF[1] = *(const bhalf8*)((P_) + abase + 4096 + co_);                      \
    AF[2] = *(const bhalf8*)((P_) + abase + 8192 + co_);                      \
    AF[3] = *(const bhalf8*)((P_) + abase + 12288 + co_);                     \
  } while (0)

#define MM(AF, BF) do {                                                       \
    __builtin_amdgcn_s_setprio(1);                                            \
    _Pragma("unroll")                                                         \
    for (int m = 0; m < 4; ++m)                                               \
      _Pragma("unroll")                                                       \
      for (int n = 0; n < 2; ++n)                                             \
        acc[m][n] = __builtin_amdgcn_mfma_f32_32x32x16_bf16(AF[m], BF[n], acc[m][n], 0, 0, 0); \
    __builtin_amdgcn_s_setprio(0);                                            \
  } while (0)

  // prologue: stage step 0 into buf0 (8 loads); certify
  stage_half(0, 0); stage_half(0, 1); stage_half(0, 2); stage_half(0, 3);
  __syncthreads();

  for (int u = 0; u < NS; ++u) {
    if (s0 && u == 16) {               // base GEMM complete -> silu in registers
      #pragma unroll
      for (int m = 0; m < 4; ++m)
        #pragma unroll
        for (int n = 0; n < 2; ++n)
          #pragma unroll
          for (int j = 0; j < 16; ++j) {
            float v = acc[m][n][j];
            acc[m][n][j] = v / (1.0f + __expf(-v));
          }
    }
    const char* p = lds + (size_t)(u & 1) * BUF_BYTES;
    const bool st = (u < NS - 1);
    // 4 clusters (kk=0..3), reads pipelined one cluster ahead, 1 half-stage each
    READF(afa, bfa, p, 0);
    if (st) stage_half(u + 1, 0);
    READF(afb, bfb, p, 1);
    MM(afa, bfa);
    if (st) stage_half(u + 1, 1);
    READF(afa, bfa, p, 2);
    MM(afb, bfb);
    if (st) stage_half(u + 1, 2);
    READF(afb, bfb, p, 3);
    MM(afa, bfa);
    if (st) stage_half(u + 1, 3);
    MM(afb, bfb);
    __syncthreads();                   // drains vm+lgkm; certifies buf[(u+1)&1]
  }
#undef READF
#undef MM

  // C/D layout (32x32, measured m74/m101): col = lane&31,
  // row = (reg&3) + 8*(reg>>2) + 4*(lane>>5)
  float* dst = s0 ? out : (P + (size_t)(split - 1) * ((size_t)B_ROWS * O_DIM));
  #pragma unroll
  for (int m = 0; m < 4; ++m)
    #pragma unroll
    for (int n = 0; n < 2; ++n) {
      const size_t rb = brow + wm * 128 + m * 32 + 4 * hi;
      const size_t c  = bcol + wn * 64 + n * 32 + lr;
      #pragma unroll
      for (int j = 0; j < 16; ++j) {
        const size_t r = rb + (j & 3) + 8 * (j >> 2);
        dst[r * O_DIM + c] = acc[m][n][j];
      }
    }
}

// ---- final: out += P0 + P1 + P2 (float4) ----
__global__ void k_reduce(float* __restrict__ out, const float* __restrict__ P) {
  const size_t i = (size_t)blockIdx.x * 256 + threadIdx.x;
  const size_t NE = (size_t)B_ROWS * O_DIM / 4;
  float4 a = ((const float4*)out)[i];
  float4 b = ((const float4*)P)[i];
  float4 c = ((const float4*)P)[i + NE];
  float4 d = ((const float4*)P)[i + 2 * NE];
  a.x += b.x + c.x + d.x;  a.y += b.y + c.y + d.y;
  a.z += b.z + c.z + d.z;  a.w += b.w + c.w + d.w;
  ((float4*)out)[i] = a;
}

extern "C" void kernel_launch(void* const* d_in, const int* in_sizes, int n_in,
                              void* d_out, int out_size, void* d_ws, size_t ws_size,
                              hipStream_t stream) {
  const float* x  = (const float*)d_in[0];   // [4096][1024]
  const float* bw = (const float*)d_in[1];   // [1024][1024]
  const float* lw = (const float*)d_in[2];   // [1024][1024][6]
  float* out = (float*)d_out;                // [4096][1024]

  char* w = (char*)d_ws;
  u16*  Ab = (u16*)(w);                                  //  8 MiB [4096][1024]
  u16*  Al = (u16*)(w + (size_t)8   * 1024 * 1024);      // 48 MiB [4096][6144]
  u16*  Bb = (u16*)(w + (size_t)56  * 1024 * 1024);      //  2 MiB [1024][1024]
  u16*  Bl = (u16*)(w + (size_t)58  * 1024 * 1024);      // 12 MiB [1024][6144]
  float* P = (float*)(w + (size_t)72 * 1024 * 1024);     // 48 MiB: 3 x [4096][1024] f32

  hipFuncSetAttribute((const void*)k_gemm,
                      hipFuncAttributeMaxDynamicSharedMemorySize, LDS_BYTES);

  k_prep  <<<dim3(2048 + B_ROWS), 256, 0, stream>>>(bw, lw, x, Bb, Bl, Ab, Al);
  k_gemm  <<<dim3(4 * (B_ROWS / BM) * (O_DIM / BN)), 512, LDS_BYTES, stream>>>(Ab, Bb, Al, Bl, out, P);
  k_reduce<<<dim3((B_ROWS * O_DIM / 4) / 256), 256, 0, stream>>>(out, P);
}

// Round 11
// 107.441 us; speedup vs baseline: 1.0992x; 1.0099x over previous
//
#include <hip/hip_runtime.h>
#include <stdint.h>

typedef unsigned short u16;
typedef unsigned int   u32;
typedef __attribute__((ext_vector_type(8)))  short bhalf8;   // 8 bf16 = 4 VGPRs
typedef __attribute__((ext_vector_type(16))) float f32x16;

#define B_ROWS 4096
#define I_DIM  1024
#define O_DIM  1024
#define N_D    6
#define K_LEG  (I_DIM * N_D)   /* 6144 */

#define BM 128
#define BN 128
#define BK 64
#define NS 56                   /* BK64 K-steps per split (112 total / 2) */
#define BUF_BYTES 32768         /* A 16KB + B 16KB */
#define LDS_BYTES 65536         /* 2 buffers -> 2 blocks/CU */

// float -> bf16 round-to-nearest-even
__device__ __forceinline__ u16 f2b(float f) {
  u32 u = __float_as_uint(f);
  return (u16)((u + 0x7fffu + ((u >> 16) & 1u)) >> 16);
}

// async global->LDS, 16B per lane; LDS dest = wave-uniform base + lane*16
__device__ __forceinline__ void gld_lds16(const void* g, void* l) {
  __builtin_amdgcn_global_load_lds(
      (const __attribute__((address_space(1))) u32*)(uintptr_t)g,
      (__attribute__((address_space(3))) u32*)(u32)(uintptr_t)l, 16, 0, 0);
}

// ---- prep (one launch):
//  blocks [0,1024):    Bb[o][i] = bf16(bw[i][o]) via 32x32 LDS tile
//  blocks [1024,2048): Bl[o][i*6+d] = bf16(lw[i][o][d]) via LDS microvector tile
//  blocks [2048,6144): per-row min/max + Legendre basis -> Ab, Al
#define RS 201
__global__ void k_prep(const float* __restrict__ bw, const float* __restrict__ lw,
                       const float* __restrict__ x,
                       u16* __restrict__ Bb, u16* __restrict__ Bl,
                       u16* __restrict__ Ab, u16* __restrict__ Al) {
  __shared__ float t[32 * RS];
  if (blockIdx.x < 1024) {
    const int bx = blockIdx.x & 31, by = blockIdx.x >> 5;
    const int i0 = by * 32, o0 = bx * 32;
    const int c = threadIdx.x & 31, r0 = threadIdx.x >> 5;
    #pragma unroll
    for (int k = 0; k < 4; ++k) {
      int r = r0 + k * 8;
      t[r * 33 + c] = bw[(size_t)(i0 + r) * O_DIM + o0 + c];
    }
    __syncthreads();
    #pragma unroll
    for (int k = 0; k < 4; ++k) {
      int r = r0 + k * 8;
      Bb[(size_t)(o0 + r) * I_DIM + i0 + c] = f2b(t[c * 33 + r]);
    }
  } else if (blockIdx.x < 2048) {
    const int blk = blockIdx.x - 1024;
    const int bx = blk & 31, by = blk >> 5;
    const int i0 = by * 32, o0 = bx * 32;
    for (int q = threadIdx.x; q < 32 * 48; q += 256) {
      int ri = q / 48, s4 = q % 48;
      float4 v = *(const float4*)(lw + (size_t)(i0 + ri) * (O_DIM * N_D) + o0 * N_D + s4 * 4);
      float* p = t + ri * RS + s4 * 4;
      p[0] = v.x; p[1] = v.y; p[2] = v.z; p[3] = v.w;
    }
    __syncthreads();
    for (int q = threadIdx.x; q < 32 * 96; q += 256) {
      int ro = q / 96, k = q % 96;
      int e0 = 2 * k, e1 = 2 * k + 1;
      float v0 = t[(e0 / 6) * RS + ro * 6 + (e0 % 6)];
      float v1 = t[(e1 / 6) * RS + ro * 6 + (e1 % 6)];
      u32* dst = (u32*)(Bl + (size_t)(o0 + ro) * K_LEG + i0 * N_D);
      dst[k] = (u32)f2b(v0) | ((u32)f2b(v1) << 16);
    }
  } else {
    const int b = blockIdx.x - 2048;
    const int tt = threadIdx.x;
    float4 v = ((const float4*)(x + (size_t)b * I_DIM))[tt];
    float mn = fminf(fminf(v.x, v.y), fminf(v.z, v.w));
    float mx = fmaxf(fmaxf(v.x, v.y), fmaxf(v.z, v.w));
    #pragma unroll
    for (int off = 32; off > 0; off >>= 1) {
      mn = fminf(mn, __shfl_xor(mn, off, 64));
      mx = fmaxf(mx, __shfl_xor(mx, off, 64));
    }
    __shared__ float smn[4], smx[4];
    if ((tt & 63) == 0) { smn[tt >> 6] = mn; smx[tt >> 6] = mx; }
    __syncthreads();
    mn = fminf(fminf(smn[0], smn[1]), fminf(smn[2], smn[3]));
    mx = fmaxf(fmaxf(smx[0], smx[1]), fmaxf(smx[2], smx[3]));
    float sc = 2.0f / (mx - mn + 1e-7f);

    float xs[4] = {v.x, v.y, v.z, v.w};
    u32 lb[12];
    #pragma unroll
    for (int e = 0; e < 4; ++e) {
      float xv = xs[e];
      float xn = (xv - mn) * sc - 1.0f;
      float p0 = 1.0f, p1 = xn;
      float p2 = (3.0f * xn * p1 - 1.0f * p0) * (1.0f / 2.0f);
      float p3 = (5.0f * xn * p2 - 2.0f * p1) * (1.0f / 3.0f);
      float p4 = (7.0f * xn * p3 - 3.0f * p2) * (1.0f / 4.0f);
      float p5 = (9.0f * xn * p4 - 4.0f * p3) * (1.0f / 5.0f);
      lb[e * 3 + 0] = (u32)f2b(xv * p0) | ((u32)f2b(xv * p1) << 16);
      lb[e * 3 + 1] = (u32)f2b(xv * p2) | ((u32)f2b(xv * p3) << 16);
      lb[e * 3 + 2] = (u32)f2b(xv * p4) | ((u32)f2b(xv * p5) << 16);
    }
    u32 a0 = (u32)f2b(xs[0]) | ((u32)f2b(xs[1]) << 16);
    u32 a1 = (u32)f2b(xs[2]) | ((u32)f2b(xs[3]) << 16);
    *(uint2*)(Ab + (size_t)b * I_DIM + tt * 4) = make_uint2(a0, a1);
    uint4* dl = (uint4*)(Al + (size_t)b * K_LEG + tt * 24);
    dl[0] = make_uint4(lb[0], lb[1], lb[2], lb[3]);
    dl[1] = make_uint4(lb[4], lb[5], lb[6], lb[7]);
    dl[2] = make_uint4(lb[8], lb[9], lb[10], lb[11]);
  }
}

// ---- fused split-K=2 GEMM: 128x128 tile, 4 waves, 32x32x16 MFMA, BK=64,
//      2-buffer LDS, 2 blocks/CU (cross-block stall hiding), counted-vmcnt +
//      raw-barrier discipline, r&7 chunk-XOR swizzle.
// split 0: base steps 0..15 (K=1024) -> silu(acc) -> leg steps [0,40)
// split 1: leg steps [40,96)
__global__ __launch_bounds__(256, 2) void k_gemm(
    const u16* __restrict__ Ab, const u16* __restrict__ Bb,
    const u16* __restrict__ Al, const u16* __restrict__ Bl,
    float* __restrict__ out, float* __restrict__ P) {
  extern __shared__ char lds[];

  const int tid  = threadIdx.x;
  const int wave = tid >> 6;
  const int lane = tid & 63;
  const int wm = wave >> 1;            // 0..1: 64-row band
  const int wn = wave & 1;             // 0..1: 64-col band
  const u32 lr = (u32)lane & 31;       // 32x32 frag row/col
  const u32 hi = (u32)lane >> 5;       // k half within 16

  const int bid   = blockIdx.x;        // 512 blocks = 2/CU
  const int bx    = bid >> 4;          // 0..31
  const int by    = (bid >> 1) & 7;    // 0..7
  const int split = bid & 1;
  const size_t brow = (size_t)bx * BM;
  const size_t bcol = (size_t)by * BN;
  const bool s0 = (split == 0);
  const int legbase = s0 ? 0 : 40;

  // staging: line h covers rows (h&3)*32 + rt of region (A: h<4, B: h>=4);
  // thread t -> (row rt = t>>3, slot t&7); source chunk pre-swizzled by row&7
  const int rt = tid >> 3;                                   // 0..31
  const u32 ct = (((u32)tid & 7) ^ ((u32)rt & 7)) * 8;       // u16 offset in row

  const u16 *gA, *gB;
  size_t ldk, ldk32;
  auto set_ptrs = [&](const u16* A, const u16* Bt, size_t ldk_, size_t kt) {
    ldk = ldk_; ldk32 = 32 * ldk_;
    gA = A  + (brow + rt) * ldk_ + kt * BK + ct;
    gB = Bt + (bcol + rt) * ldk_ + kt * BK + ct;
  };
  if (s0) set_ptrs(Ab, Bb, I_DIM, 0);
  else    set_ptrs(Al, Bl, K_LEG, (size_t)legbase);

  // stage line h (0-3: A, 4-7: B) of K-step v into buf[v&1]
  auto stg = [&](int v, int h) {
    if (s0 && v == 16 && h == 0) set_ptrs(Al, Bl, K_LEG, 0);
    char* dst = lds + (size_t)(v & 1) * BUF_BYTES + ((h >= 4) ? 16384 : 0)
              + (size_t)(h & 3) * 4096 + (size_t)tid * 16;
    const u16* src = ((h < 4) ? gA : gB) + (size_t)(h & 3) * ldk32;
    gld_lds16(src, dst);
    if (h == 7) { gA += BK; gB += BK; }
  };

  // frag reads: row r stores chunk c at slot c^(r&7); r&7 == lane&7 here.
  // chunk(kk) = (kk<<1)|hi  ->  byte = (((hi^(lane&7))*16) ^ (kk<<5))
  const u32 c0off = (hi ^ ((u32)lane & 7)) * 16;
  const u32 abase = ((u32)wm * 64 + lr) * 128;
  const u32 bbase = 16384u + ((u32)wn * 64 + lr) * 128;

  f32x16 acc[2][2] = {};
  bhalf8 fa0[2], fb0[2], fa1[2], fb1[2], fa2[2], fb2[2], fa3[2], fb3[2];

#define READF(AF, BF, P_, KK) do {                                            \
    const u32 co_ = c0off ^ ((KK) << 5);                                      \
    BF[0] = *(const bhalf8*)((P_) + bbase + co_);                             \
    BF[1] = *(const bhalf8*)((P_) + bbase + 4096 + co_);                      \
    AF[0] = *(const bhalf8*)((P_) + abase + co_);                             \
    AF[1] = *(const bhalf8*)((P_) + abase + 4096 + co_);                      \
  } while (0)

#define MM(AF, BF) do {                                                       \
    __builtin_amdgcn_s_setprio(1);                                            \
    _Pragma("unroll")                                                         \
    for (int m = 0; m < 2; ++m)                                               \
      _Pragma("unroll")                                                       \
      for (int n = 0; n < 2; ++n)                                             \
        acc[m][n] = __builtin_amdgcn_mfma_f32_32x32x16_bf16(AF[m], BF[n], acc[m][n], 0, 0, 0); \
    __builtin_amdgcn_s_setprio(0);                                            \
  } while (0)

  // prologue: stage step 0 into buf0; full certify once
  #pragma unroll
  for (int h = 0; h < 8; ++h) stg(0, h);
  __syncthreads();

  for (int u = 0; u < NS; ++u) {
    if (s0 && u == 16) {               // base GEMM complete -> silu in registers
      #pragma unroll
      for (int m = 0; m < 2; ++m)
        #pragma unroll
        for (int n = 0; n < 2; ++n)
          #pragma unroll
          for (int j = 0; j < 16; ++j) {
            float v = acc[m][n][j];
            acc[m][n][j] = v / (1.0f + __expf(-v));
          }
    }
    const char* p = lds + (size_t)(u & 1) * BUF_BYTES;
    const bool st = (u < NS - 1);
    // 4 clusters (kk=0..3): reads one cluster ahead, 2 stage-lines per cluster
    READF(fa0, fb0, p, 0);
    if (st) { stg(u + 1, 0); stg(u + 1, 1); }
    READF(fa1, fb1, p, 1);
    MM(fa0, fb0);
    if (st) { stg(u + 1, 2); stg(u + 1, 3); }
    READF(fa2, fb2, p, 2);
    MM(fa1, fb1);
    if (st) { stg(u + 1, 4); stg(u + 1, 5); }
    READF(fa3, fb3, p, 3);
    MM(fa2, fb2);
    if (st) { stg(u + 1, 6); stg(u + 1, 7); }
    MM(fa3, fb3);
    // loads for u+1 were issued ~a full step ago -> vmcnt(0) is cheap;
    // raw barrier (no lgkm drain); sched fence stops read hoisting (rule #18)
    asm volatile("s_waitcnt vmcnt(0)" ::: "memory");
    __builtin_amdgcn_s_barrier();
    __builtin_amdgcn_sched_barrier(0);
  }
#undef READF
#undef MM

  // C/D layout (32x32, measured m74/m101): col = lane&31,
  // row = (reg&3) + 8*(reg>>2) + 4*(lane>>5)
  float* dst = s0 ? out : P;
  #pragma unroll
  for (int m = 0; m < 2; ++m)
    #pragma unroll
    for (int n = 0; n < 2; ++n) {
      const size_t rb = brow + wm * 64 + m * 32 + 4 * hi;
      const size_t c  = bcol + wn * 64 + n * 32 + lr;
      #pragma unroll
      for (int j = 0; j < 16; ++j) {
        const size_t r = rb + (j & 3) + 8 * (j >> 2);
        dst[r * O_DIM + c] = acc[m][n][j];
      }
    }
}

// ---- final: out += P (float4) ----
__global__ void k_reduce(float* __restrict__ out, const float* __restrict__ P) {
  const size_t i = (size_t)blockIdx.x * 256 + threadIdx.x;
  float4 a = ((const float4*)out)[i];
  float4 b = ((const float4*)P)[i];
  a.x += b.x;  a.y += b.y;  a.z += b.z;  a.w += b.w;
  ((float4*)out)[i] = a;
}

extern "C" void kernel_launch(void* const* d_in, const int* in_sizes, int n_in,
                              void* d_out, int out_size, void* d_ws, size_t ws_size,
                              hipStream_t stream) {
  const float* x  = (const float*)d_in[0];   // [4096][1024]
  const float* bw = (const float*)d_in[1];   // [1024][1024]
  const float* lw = (const float*)d_in[2];   // [1024][1024][6]
  float* out = (float*)d_out;                // [4096][1024]

  char* w = (char*)d_ws;
  u16*  Ab = (u16*)(w);                                  //  8 MiB [4096][1024]
  u16*  Al = (u16*)(w + (size_t)8   * 1024 * 1024);      // 48 MiB [4096][6144]
  u16*  Bb = (u16*)(w + (size_t)56  * 1024 * 1024);      //  2 MiB [1024][1024]
  u16*  Bl = (u16*)(w + (size_t)58  * 1024 * 1024);      // 12 MiB [1024][6144]
  float* P = (float*)(w + (size_t)72 * 1024 * 1024);     // 16 MiB [4096][1024] f32

  hipFuncSetAttribute((const void*)k_gemm,
                      hipFuncAttributeMaxDynamicSharedMemorySize, LDS_BYTES);

  k_prep  <<<dim3(2048 + B_ROWS), 256, 0, stream>>>(bw, lw, x, Bb, Bl, Ab, Al);
  k_gemm  <<<dim3(2 * (B_ROWS / BM) * (O_DIM / BN)), 256, LDS_BYTES, stream>>>(Ab, Bb, Al, Bl, out, P);
  k_reduce<<<dim3((B_ROWS * O_DIM / 4) / 256), 256, 0, stream>>>(out, P);
}

// Round 12
// 103.213 us; speedup vs baseline: 1.1443x; 1.0410x over previous
//
#include <hip/hip_runtime.h>
#include <stdint.h>

typedef unsigned short u16;
typedef unsigned int   u32;
typedef __attribute__((ext_vector_type(8))) short bhalf8;   // 8 bf16 = 4 VGPRs
typedef __attribute__((ext_vector_type(4))) float f32x4;

#define B_ROWS 4096
#define I_DIM  1024
#define O_DIM  1024
#define N_D    6
#define K_LEG  (I_DIM * N_D)   /* 6144 */

#define NU 28                  /* BK64 K-tiles per split (112 total / 4) */
#define LDS_BYTES 131072       /* 2 dbuf x (A 32KB + B 32KB) */

// float -> bf16 round-to-nearest-even
__device__ __forceinline__ u16 f2b(float f) {
  u32 u = __float_as_uint(f);
  return (u16)((u + 0x7fffu + ((u >> 16) & 1u)) >> 16);
}
__device__ __forceinline__ float b2f(u16 h) {
  return __uint_as_float((u32)h << 16);
}

// async global->LDS, 16B per lane
__device__ __forceinline__ void gld_lds16(const void* g, void* l) {
  __builtin_amdgcn_global_load_lds(
      (const __attribute__((address_space(1))) u32*)(uintptr_t)g,
      (__attribute__((address_space(3))) u32*)(u32)(uintptr_t)l, 16, 0, 0);
}

// ---- prep (one launch):
//  blocks [0,1024):    Bb[o][i] = bf16(bw[i][o]) via 32x32 LDS tile
//  blocks [1024,2048): Bl[o][i*6+d] = bf16(lw[i][o][d]) via LDS microvector tile
//  blocks [2048,6144): per-row min/max + Legendre basis -> Ab, Al
#define RS 201
__global__ void k_prep(const float* __restrict__ bw, const float* __restrict__ lw,
                       const float* __restrict__ x,
                       u16* __restrict__ Bb, u16* __restrict__ Bl,
                       u16* __restrict__ Ab, u16* __restrict__ Al) {
  __shared__ float t[32 * RS];
  if (blockIdx.x < 1024) {
    const int bx = blockIdx.x & 31, by = blockIdx.x >> 5;
    const int i0 = by * 32, o0 = bx * 32;
    const int c = threadIdx.x & 31, r0 = threadIdx.x >> 5;
    #pragma unroll
    for (int k = 0; k < 4; ++k) {
      int r = r0 + k * 8;
      t[r * 33 + c] = bw[(size_t)(i0 + r) * O_DIM + o0 + c];
    }
    __syncthreads();
    #pragma unroll
    for (int k = 0; k < 4; ++k) {
      int r = r0 + k * 8;
      Bb[(size_t)(o0 + r) * I_DIM + i0 + c] = f2b(t[c * 33 + r]);
    }
  } else if (blockIdx.x < 2048) {
    const int blk = blockIdx.x - 1024;
    const int bx = blk & 31, by = blk >> 5;
    const int i0 = by * 32, o0 = bx * 32;
    for (int q = threadIdx.x; q < 32 * 48; q += 256) {
      int ri = q / 48, s4 = q % 48;
      float4 v = *(const float4*)(lw + (size_t)(i0 + ri) * (O_DIM * N_D) + o0 * N_D + s4 * 4);
      float* p = t + ri * RS + s4 * 4;
      p[0] = v.x; p[1] = v.y; p[2] = v.z; p[3] = v.w;
    }
    __syncthreads();
    for (int q = threadIdx.x; q < 32 * 96; q += 256) {
      int ro = q / 96, k = q % 96;
      int e0 = 2 * k, e1 = 2 * k + 1;
      float v0 = t[(e0 / 6) * RS + ro * 6 + (e0 % 6)];
      float v1 = t[(e1 / 6) * RS + ro * 6 + (e1 % 6)];
      u32* dst = (u32*)(Bl + (size_t)(o0 + ro) * K_LEG + i0 * N_D);
      dst[k] = (u32)f2b(v0) | ((u32)f2b(v1) << 16);
    }
  } else {
    const int b = blockIdx.x - 2048;
    const int tt = threadIdx.x;
    float4 v = ((const float4*)(x + (size_t)b * I_DIM))[tt];
    float mn = fminf(fminf(v.x, v.y), fminf(v.z, v.w));
    float mx = fmaxf(fmaxf(v.x, v.y), fmaxf(v.z, v.w));
    #pragma unroll
    for (int off = 32; off > 0; off >>= 1) {
      mn = fminf(mn, __shfl_xor(mn, off, 64));
      mx = fmaxf(mx, __shfl_xor(mx, off, 64));
    }
    __shared__ float smn[4], smx[4];
    if ((tt & 63) == 0) { smn[tt >> 6] = mn; smx[tt >> 6] = mx; }
    __syncthreads();
    mn = fminf(fminf(smn[0], smn[1]), fminf(smn[2], smn[3]));
    mx = fmaxf(fmaxf(smx[0], smx[1]), fmaxf(smx[2], smx[3]));
    float sc = 2.0f / (mx - mn + 1e-7f);

    float xs[4] = {v.x, v.y, v.z, v.w};
    u32 lb[12];
    #pragma unroll
    for (int e = 0; e < 4; ++e) {
      float xv = xs[e];
      float xn = (xv - mn) * sc - 1.0f;
      float p0 = 1.0f, p1 = xn;
      float p2 = (3.0f * xn * p1 - 1.0f * p0) * (1.0f / 2.0f);
      float p3 = (5.0f * xn * p2 - 2.0f * p1) * (1.0f / 3.0f);
      float p4 = (7.0f * xn * p3 - 3.0f * p2) * (1.0f / 4.0f);
      float p5 = (9.0f * xn * p4 - 4.0f * p3) * (1.0f / 5.0f);
      lb[e * 3 + 0] = (u32)f2b(xv * p0) | ((u32)f2b(xv * p1) << 16);
      lb[e * 3 + 1] = (u32)f2b(xv * p2) | ((u32)f2b(xv * p3) << 16);
      lb[e * 3 + 2] = (u32)f2b(xv * p4) | ((u32)f2b(xv * p5) << 16);
    }
    u32 a0 = (u32)f2b(xs[0]) | ((u32)f2b(xs[1]) << 16);
    u32 a1 = (u32)f2b(xs[2]) | ((u32)f2b(xs[3]) << 16);
    *(uint2*)(Ab + (size_t)b * I_DIM + tt * 4) = make_uint2(a0, a1);
    uint4* dl = (uint4*)(Al + (size_t)b * K_LEG + tt * 24);
    dl[0] = make_uint4(lb[0], lb[1], lb[2], lb[3]);
    dl[1] = make_uint4(lb[4], lb[5], lb[6], lb[7]);
    dl[2] = make_uint4(lb[8], lb[9], lb[10], lb[11]);
  }
}

// ---- fused split-K=4 GEMM: 256x256, 8 waves, 16x16x32 MFMA, BK=64,
//      m201-faithful 4-phase/K-tile schedule: per phase {reads for NEXT
//      phase's MFMA; stage 1 half-tile into region dead 1 phase ago; counted
//      vmcnt; bar; counted lgkm; 16 MFMA; bar}. No vmcnt(0)/lgkm(0) in loop.
// halves: h0=Akk0 h1=Bkk0 h2=Akk1 h3=Bkk1; stream per tile u:
//   P1(u)->Bkk1(u+1), P2(u)->Akk0(u+2), P3(u)->Bkk0(u+2), P4(u)->Akk1(u+2)
__global__ __launch_bounds__(512, 2) void k_gemm(
    const u16* __restrict__ Ab, const u16* __restrict__ Bb,
    const u16* __restrict__ Al, const u16* __restrict__ Bl,
    float* __restrict__ out, u16* __restrict__ Pb) {
  extern __shared__ char lds[];

  const int tid  = threadIdx.x;
  const int wave = tid >> 6;
  const int lane = tid & 63;
  const int wm = wave >> 2;            // 0..1: 128-row band
  const int wn = wave & 3;             // 0..3: 64-col band
  const u32 l15 = (u32)lane & 15;

  const int bid   = blockIdx.x;        // 256 blocks = 1/CU
  const int bx    = bid >> 4;
  const int by    = (bid >> 2) & 3;
  const int split = bid & 3;
  const size_t brow = (size_t)bx * 256;
  const size_t bcol = (size_t)by * 256;
  const bool s0 = (split == 0);
  const int legbase = s0 ? 0 : (12 + 28 * (split - 1));

  // staging: thread t -> row rS=t>>2 (of 128-row call), chunk-pos t&3;
  // source chunk pre-swizzled by (row>>1)&3 (call-invariant)
  const int rS = tid >> 2;
  const u32 cS = (((u32)tid & 3) ^ (((u32)rS >> 1) & 3)) * 8;

  auto stage = [&](int v, int h) {
    const int isB = h & 1, kkh = h >> 1;
    char* dst = lds + ((v & 1) * 65536 + isB * 32768 + kkh * 16384) + (size_t)tid * 16;
    const u16* M; size_t ldk; int kt;
    if (s0 && v < 16) { M = isB ? Bb : Ab; ldk = I_DIM; kt = v; }
    else { M = isB ? Bl : Al; ldk = K_LEG; kt = s0 ? (v - 16) : (legbase + v); }
    const u16* src = M + ((isB ? bcol : brow) + (size_t)rS) * ldk
                   + (size_t)kt * 64 + kkh * 32 + cS;
    gld_lds16(src, dst);
    gld_lds16(src + 128 * ldk, dst + 8192);
  };

  // frag reads: row r stores chunk c at pos c ^ ((r>>1)&3); key = (l15>>1)&3
  const u32 chnk = ((((u32)lane >> 4) & 3) ^ ((l15 >> 1) & 3)) * 16;
  const u32 aoff = ((u32)wm * 128 + l15) * 64 + chnk;            // + m*1024 + kkh*16384
  const u32 boff = 32768u + ((u32)wn * 64 + l15) * 64 + chnk;    // + n*1024 + kkh*16384

  f32x4 acc[8][4] = {};
  bhalf8 Aev[8], Aod[8], Bn01[2], Bn23[2];

  auto silu = [&]() {
    #pragma unroll
    for (int m = 0; m < 8; ++m)
      #pragma unroll
      for (int n = 0; n < 4; ++n)
        #pragma unroll
        for (int j = 0; j < 4; ++j) {
          float v = acc[m][n][j];
          acc[m][n][j] = v / (1.0f + __expf(-v));
        }
  };

#define SB   __builtin_amdgcn_sched_barrier(0)
#define BARR __builtin_amdgcn_s_barrier()
#define VMW(N) asm volatile("s_waitcnt vmcnt(" #N ")" ::: "memory")
#define RD_A(SET, DB, KKH) do { const char* q_ = lds + (DB) + (KKH)*16384 + aoff; \
    SET[0]=*(const bhalf8*)(q_);      SET[1]=*(const bhalf8*)(q_+1024);       \
    SET[2]=*(const bhalf8*)(q_+2048); SET[3]=*(const bhalf8*)(q_+3072);       \
    SET[4]=*(const bhalf8*)(q_+4096); SET[5]=*(const bhalf8*)(q_+5120);       \
    SET[6]=*(const bhalf8*)(q_+6144); SET[7]=*(const bhalf8*)(q_+7168); } while(0)
#define RD_B01(DB, KKH) do { const char* q_ = lds + (DB) + (KKH)*16384 + boff; \
    Bn01[0]=*(const bhalf8*)(q_);      Bn01[1]=*(const bhalf8*)(q_+1024); } while(0)
#define RD_B23(DB, KKH) do { const char* q_ = lds + (DB) + (KKH)*16384 + boff; \
    Bn23[0]=*(const bhalf8*)(q_+2048); Bn23[1]=*(const bhalf8*)(q_+3072); } while(0)
#define MFMA8(ASET, B0_, B1_, NB) do {                                        \
    __builtin_amdgcn_s_setprio(1);                                            \
    _Pragma("unroll")                                                         \
    for (int m_ = 0; m_ < 8; ++m_) {                                          \
      acc[m_][NB]   = __builtin_amdgcn_mfma_f32_16x16x32_bf16(ASET[m_], B0_, acc[m_][NB],   0,0,0); \
      acc[m_][NB+1] = __builtin_amdgcn_mfma_f32_16x16x32_bf16(ASET[m_], B1_, acc[m_][NB+1], 0,0,0); \
    }                                                                         \
    __builtin_amdgcn_s_setprio(0);                                            \
  } while(0)

  // MFMA at phase p consumes reads issued at p-1 (counted lgkm certifies them):
  // M1=Aev*B01kk0, M2=Aev*B23kk0, M3=Aod*B01kk1, M4=Aod*B23kk1
#define PH1(DB, STG, WT) do { RD_B23(DB, 0); STG; SB; WT; BARR;               \
    asm volatile("s_waitcnt lgkmcnt(2)" ::: "memory"); SB;                    \
    MFMA8(Aev, Bn01[0], Bn01[1], 0); BARR; } while(0)
#define PH2(DB, STG, WT) do { RD_A(Aod, DB, 1); RD_B01(DB, 1); STG; SB; WT; BARR; \
    asm volatile("s_waitcnt lgkmcnt(10)" ::: "memory"); SB;                   \
    MFMA8(Aev, Bn23[0], Bn23[1], 2); BARR; } while(0)
#define PH3(DB, STG, WT) do { RD_B23(DB, 1); STG; SB; WT; BARR;               \
    asm volatile("s_waitcnt lgkmcnt(2)" ::: "memory"); SB;                    \
    MFMA8(Aod, Bn01[0], Bn01[1], 0); BARR; } while(0)
#define PH4(DB2, STG) do { RD_A(Aev, DB2, 0); RD_B01(DB2, 0); STG; SB; BARR;  \
    asm volatile("s_waitcnt lgkmcnt(10)" ::: "memory"); SB;                   \
    MFMA8(Aod, Bn23[0], Bn23[1], 2); BARR; } while(0)
#define PH4LAST() do {                                                        \
    asm volatile("s_waitcnt lgkmcnt(0)" ::: "memory"); SB;                    \
    MFMA8(Aod, Bn23[0], Bn23[1], 2); } while(0)

  // prologue: stage tile0 (4 halves) + tile1 (Akk0,Bkk0,Akk1) = 14 loads;
  // vmcnt(6) -> tile0 landed; then read M1(0) operands (10 ds_reads)
  stage(0, 0); stage(0, 1); stage(0, 2); stage(0, 3);
  stage(1, 0); stage(1, 1); stage(1, 2);
  VMW(6); BARR;
  RD_A(Aev, 0u, 0); RD_B01(0u, 0);

  for (int u = 0; u < NU - 2; ++u) {   // u = 0..25, all-steady
    if (s0 && u == 16) silu();
    const u32 db  = (u & 1) ? 65536u : 0u;
    const u32 db2 = 65536u - db;
    PH1(db, stage(u + 1, 3), VMW(10));
    PH2(db, stage(u + 2, 0), VMW(10));
    PH3(db, stage(u + 2, 1), VMW(8));
    PH4(db2, stage(u + 2, 2));
  }
  // u = 26 (db=0): last stage is Bkk1(27) in P1
  PH1(0u, stage(27, 3), VMW(10));
  PH2(0u, (void)0, VMW(8));
  PH3(0u, (void)0, VMW(4));
  PH4(65536u, (void)0);
  // u = 27 (db=65536): drain
  PH1(65536u, (void)0, VMW(2));
  PH2(65536u, (void)0, VMW(0));
  PH3(65536u, (void)0, (void)0);
  PH4LAST();

#undef PH1
#undef PH2
#undef PH3
#undef PH4
#undef PH4LAST
#undef MFMA8
#undef RD_A
#undef RD_B01
#undef RD_B23

  // C/D layout (16x16, measured m89/m91): col = lane&15, row = (lane>>4)*4 + j
  if (s0) {
    #pragma unroll
    for (int m = 0; m < 8; ++m)
      #pragma unroll
      for (int n = 0; n < 4; ++n) {
        const size_t r0 = brow + wm * 128 + m * 16 + (lane >> 4) * 4;
        const size_t c  = bcol + wn * 64 + n * 16 + l15;
        #pragma unroll
        for (int j = 0; j < 4; ++j)
          out[(r0 + j) * O_DIM + c] = acc[m][n][j];
      }
  } else {
    u16* dst = Pb + (size_t)(split - 1) * ((size_t)B_ROWS * O_DIM);
    #pragma unroll
    for (int m = 0; m < 8; ++m)
      #pragma unroll
      for (int n = 0; n < 4; ++n) {
        const size_t r0 = brow + wm * 128 + m * 16 + (lane >> 4) * 4;
        const size_t c  = bcol + wn * 64 + n * 16 + l15;
        #pragma unroll
        for (int j = 0; j < 4; ++j)
          dst[(r0 + j) * O_DIM + c] = f2b(acc[m][n][j]);
      }
  }
}

// ---- final: out += Pb0 + Pb1 + Pb2 (bf16 partials) ----
__global__ void k_reduce(float* __restrict__ out, const u16* __restrict__ Pb) {
  const size_t i = (size_t)blockIdx.x * 256 + threadIdx.x;   // per float4
  const size_t NE = (size_t)B_ROWS * O_DIM;
  float4 a = ((const float4*)out)[i];
  ushort4 p0 = ((const ushort4*)Pb)[i];
  ushort4 p1 = ((const ushort4*)(Pb + NE))[i];
  ushort4 p2 = ((const ushort4*)(Pb + 2 * NE))[i];
  a.x += b2f(p0.x) + b2f(p1.x) + b2f(p2.x);
  a.y += b2f(p0.y) + b2f(p1.y) + b2f(p2.y);
  a.z += b2f(p0.z) + b2f(p1.z) + b2f(p2.z);
  a.w += b2f(p0.w) + b2f(p1.w) + b2f(p2.w);
  ((float4*)out)[i] = a;
}

extern "C" void kernel_launch(void* const* d_in, const int* in_sizes, int n_in,
                              void* d_out, int out_size, void* d_ws, size_t ws_size,
                              hipStream_t stream) {
  const float* x  = (const float*)d_in[0];   // [4096][1024]
  const float* bw = (const float*)d_in[1];   // [1024][1024]
  const float* lw = (const float*)d_in[2];   // [1024][1024][6]
  float* out = (float*)d_out;                // [4096][1024]

  char* w = (char*)d_ws;
  u16* Ab = (u16*)(w);                                  //  8 MiB [4096][1024]
  u16* Al = (u16*)(w + (size_t)8   * 1024 * 1024);      // 48 MiB [4096][6144]
  u16* Bb = (u16*)(w + (size_t)56  * 1024 * 1024);      //  2 MiB [1024][1024]
  u16* Bl = (u16*)(w + (size_t)58  * 1024 * 1024);      // 12 MiB [1024][6144]
  u16* Pb = (u16*)(w + (size_t)72  * 1024 * 1024);      // 24 MiB: 3 x [4096][1024] bf16

  hipFuncSetAttribute((const void*)k_gemm,
                      hipFuncAttributeMaxDynamicSharedMemorySize, LDS_BYTES);

  k_prep  <<<dim3(2048 + B_ROWS), 256, 0, stream>>>(bw, lw, x, Bb, Bl, Ab, Al);
  k_gemm  <<<dim3(256), 512, LDS_BYTES, stream>>>(Ab, Bb, Al, Bl, out, Pb);
  k_reduce<<<dim3((B_ROWS * O_DIM / 4) / 256), 256, 0, stream>>>(out, Pb);
}